// Round 5
// baseline (301.165 us; speedup 1.0000x reference)
//
#include <hip/hip_runtime.h>
#include <math.h>

// Problem constants
#define B_ 2
#define L_ 1000
#define D_ 288
#define H_ 8
#define DIM_ 36
#define DFF_ 576
#define KS_ 250
#define NQ_ 250
#define BH_ (B_ * H_)
#define EPS_ 1e-5f
#define PSTRIDE_ 40             // partial row: 36 acc + 1 sum, padded to 40
#define MAXCL_ 125              // max chunk_len (small-ws fallback)

__device__ __forceinline__ float gelu_exact(float x) {
    return 0.5f * x * (1.0f + erff(x * 0.70710678118654752f));
}

__device__ __forceinline__ float dot4(float4 a, float4 b) {
    return a.x * b.x + a.y * b.y + a.z * b.z + a.w * b.w;
}

// ---------------------------------------------------------------------------
// K0: merged weight prep: QKV transpose (blocks 0..242) + FFN transpose
// (blocks 243..566). One launch at stream start.
// ---------------------------------------------------------------------------
__global__ __launch_bounds__(256) void weights_prep_kernel(
    const float* __restrict__ Wq, const float* __restrict__ Wk,
    const float* __restrict__ Wv,
    float* __restrict__ WqT, float* __restrict__ WkT, float* __restrict__ WvT,
    const float* __restrict__ W1, const float* __restrict__ W2,
    float* __restrict__ W1T, float* __restrict__ W2T)
{
    __shared__ float tile[32][33];
    const int tx = threadIdx.x & 31, ty = threadIdx.x >> 5;
    if (blockIdx.x < 243) {
        const int m = blockIdx.x / 81;
        const int t = blockIdx.x % 81;
        const float* src = (m == 0) ? Wq : (m == 1) ? Wk : Wv;
        float* dst = (m == 0) ? WqT : (m == 1) ? WkT : WvT;
        const int ty0 = (t / 9) * 32, tx0 = (t % 9) * 32;
#pragma unroll
        for (int i = 0; i < 4; i++)
            tile[ty + 8 * i][tx] = src[(size_t)(ty0 + ty + 8 * i) * D_ + tx0 + tx];
        __syncthreads();
#pragma unroll
        for (int i = 0; i < 4; i++)
            dst[(size_t)(tx0 + ty + 8 * i) * D_ + ty0 + tx] = tile[tx][ty + 8 * i];
    } else {
        int t = blockIdx.x - 243;
        const float* src; float* dst; int Rr, Cc, ntx;
        if (t < 162) { src = W1; dst = W1T; Rr = DFF_; Cc = D_; ntx = 9; }
        else { t -= 162; src = W2; dst = W2T; Rr = D_; Cc = DFF_; ntx = 18; }
        const int ty0 = (t / ntx) * 32, tx0 = (t % ntx) * 32;
#pragma unroll
        for (int i = 0; i < 4; i++)
            tile[ty + 8 * i][tx] = src[(size_t)(ty0 + ty + 8 * i) * Cc + tx0 + tx];
        __syncthreads();
#pragma unroll
        for (int i = 0; i < 4; i++)
            dst[(size_t)(tx0 + ty + 8 * i) * Rr + ty0 + tx] = tile[tx][ty + 8 * i];
    }
}

// ---------------------------------------------------------------------------
// K1 v4: QKV, R=8 rows/block (halves weight L2 traffic vs v3: 249 MB).
// grid 250, block 512: 432 active = 216 col-groups x 2 k-groups of 144.
// All xsT reads are wave-uniform broadcasts. Emits KT directly.
// ---------------------------------------------------------------------------
__global__ __launch_bounds__(512) void qkvT4_kernel(
    const float* __restrict__ x,
    const float* __restrict__ WqT, const float* __restrict__ WkT,
    const float* __restrict__ WvT,
    const float* __restrict__ bq, const float* __restrict__ bk,
    const float* __restrict__ bv,
    float* __restrict__ Q, float* __restrict__ K, float* __restrict__ V,
    float* __restrict__ KT)
{
    __shared__ float xsT[D_][8];        // [k][r]  9216 B
    __shared__ float red[6912];         // kg1 partials 27648 B
    const int base = blockIdx.x * 8;
    const int tid = threadIdx.x;

    for (int idx = tid; idx < 8 * D_; idx += 512) {
        int r = idx / D_, k = idx % D_;
        xsT[k][r] = x[(size_t)(base + r) * D_ + k];
    }
    __syncthreads();

    const int kg = tid / 216;           // 0 or 1 (tid < 432)
    const int ct = tid - kg * 216;      // 0..215
    const bool active = tid < 432;

    float a[4][8];
    int m = 0, c = 0;
    if (active) {
        const int gcol = 4 * ct;              // 0..863
        m = gcol / D_;
        c = gcol - m * D_;
        const float* WT = (m == 0) ? WqT : (m == 1) ? WkT : WvT;
        const float* bias = (m == 0) ? bq : (m == 1) ? bk : bv;
#pragma unroll
        for (int j = 0; j < 4; j++) {
            float bv2 = (kg == 0) ? bias[c + j] : 0.f;
#pragma unroll
            for (int r = 0; r < 8; r++) a[j][r] = bv2;
        }
        const int kbeg = kg * 144;
        for (int k = kbeg; k < kbeg + 144; k++) {
            float4 w = *(const float4*)(WT + (size_t)k * D_ + c);
            float4 x0 = *(const float4*)&xsT[k][0];   // broadcast
            float4 x1 = *(const float4*)&xsT[k][4];   // broadcast
            a[0][0] += w.x * x0.x; a[0][1] += w.x * x0.y; a[0][2] += w.x * x0.z; a[0][3] += w.x * x0.w;
            a[0][4] += w.x * x1.x; a[0][5] += w.x * x1.y; a[0][6] += w.x * x1.z; a[0][7] += w.x * x1.w;
            a[1][0] += w.y * x0.x; a[1][1] += w.y * x0.y; a[1][2] += w.y * x0.z; a[1][3] += w.y * x0.w;
            a[1][4] += w.y * x1.x; a[1][5] += w.y * x1.y; a[1][6] += w.y * x1.z; a[1][7] += w.y * x1.w;
            a[2][0] += w.z * x0.x; a[2][1] += w.z * x0.y; a[2][2] += w.z * x0.z; a[2][3] += w.z * x0.w;
            a[2][4] += w.z * x1.x; a[2][5] += w.z * x1.y; a[2][6] += w.z * x1.z; a[2][7] += w.z * x1.w;
            a[3][0] += w.w * x0.x; a[3][1] += w.w * x0.y; a[3][2] += w.w * x0.z; a[3][3] += w.w * x0.w;
            a[3][4] += w.w * x1.x; a[3][5] += w.w * x1.y; a[3][6] += w.w * x1.z; a[3][7] += w.w * x1.w;
        }
        if (kg == 1) {
#pragma unroll
            for (int j = 0; j < 4; j++) {
                *(float4*)&red[(j * 216 + ct) * 8 + 0] =
                    make_float4(a[j][0], a[j][1], a[j][2], a[j][3]);
                *(float4*)&red[(j * 216 + ct) * 8 + 4] =
                    make_float4(a[j][4], a[j][5], a[j][6], a[j][7]);
            }
        }
    }
    __syncthreads();

    if (active && kg == 0) {
        const int bb_ = base / L_;             // block never spans b boundary
        const int l0 = base % L_;
        float* outp = (m == 0) ? Q : (m == 1) ? K : V;
#pragma unroll
        for (int j = 0; j < 4; j++) {
            float4 o0 = *(const float4*)&red[(j * 216 + ct) * 8 + 0];
            float4 o1 = *(const float4*)&red[(j * 216 + ct) * 8 + 4];
            a[j][0] += o0.x; a[j][1] += o0.y; a[j][2] += o0.z; a[j][3] += o0.w;
            a[j][4] += o1.x; a[j][5] += o1.y; a[j][6] += o1.z; a[j][7] += o1.w;
            int col = c + j;
            int h = col / DIM_, dd = col % DIM_;
#pragma unroll
            for (int r = 0; r < 8; r++) {
                int row = base + r;
                int b = row / L_, l = row % L_;
                outp[((size_t)(b * H_ + h) * L_ + l) * DIM_ + dd] = a[j][r];
            }
            if (m == 1) {
                float* kt = KT + ((size_t)(bb_ * H_ + h) * DIM_ + dd) * L_ + l0;
                *(float4*)kt = make_float4(a[j][0], a[j][1], a[j][2], a[j][3]);
                *(float4*)(kt + 4) = make_float4(a[j][4], a[j][5], a[j][6], a[j][7]);
            }
        }
    }
}

// ---------------------------------------------------------------------------
// K1-fallback: qkv with row-major weights (small-ws path, no KT).
// ---------------------------------------------------------------------------
__global__ __launch_bounds__(320) void qkv_kernel(
    const float* __restrict__ x,
    const float* __restrict__ Wq, const float* __restrict__ bq,
    const float* __restrict__ Wk, const float* __restrict__ bk,
    const float* __restrict__ Wv, const float* __restrict__ bv,
    float* __restrict__ Q, float* __restrict__ K, float* __restrict__ V)
{
    constexpr int R = 8;
    __shared__ float xs[R][D_];
    const int base = blockIdx.x * R;
    const int tid = threadIdx.x;

    const float4* xsrc = (const float4*)(x + (size_t)base * D_);
    float4* xdst = (float4*)&xs[0][0];
    for (int i = tid; i < R * D_ / 4; i += 320) xdst[i] = xsrc[i];
    __syncthreads();

    if (tid < D_) {
        const float4* wq4 = (const float4*)(Wq + (size_t)tid * D_);
        const float4* wk4 = (const float4*)(Wk + (size_t)tid * D_);
        const float4* wv4 = (const float4*)(Wv + (size_t)tid * D_);
        float aq[R], ak[R], av[R];
        float biasq = bq[tid], biask = bk[tid], biasv = bv[tid];
#pragma unroll
        for (int r = 0; r < R; r++) { aq[r] = biasq; ak[r] = biask; av[r] = biasv; }
        for (int d4 = 0; d4 < D_ / 4; d4++) {
            float4 wqv = wq4[d4], wkv = wk4[d4], wvv = wv4[d4];
#pragma unroll
            for (int r = 0; r < R; r++) {
                float4 hv = *(const float4*)&xs[r][d4 * 4];
                aq[r] += dot4(hv, wqv);
                ak[r] += dot4(hv, wkv);
                av[r] += dot4(hv, wvv);
            }
        }
        const int h = tid / DIM_, dd = tid % DIM_;
#pragma unroll
        for (int r = 0; r < R; r++) {
            int row = base + r;
            int b = row / L_, l = row % L_;
            size_t o = ((size_t)(b * H_ + h) * L_ + l) * DIM_ + dd;
            Q[o] = aq[r]; K[o] = ak[r]; V[o] = av[r];
        }
    }
}

// ---------------------------------------------------------------------------
// K3 v4: score+measure, 8 keys/thread (block 128, 125 active). grid 2000.
// ---------------------------------------------------------------------------
__global__ __launch_bounds__(128) void score_measure4_kernel(
    const float* __restrict__ Q, const float* __restrict__ KT,
    const int* __restrict__ index_key, float* __restrict__ measure)
{
    __shared__ float qs[8][DIM_];       // 1152 B
    __shared__ float st[8][1004];       // 32128 B
    const int bh = blockIdx.x / 125;
    const int qt = blockIdx.x % 125;
    const int tid = threadIdx.x;

    if (tid < 72)
        ((float4*)&qs[0][0])[tid] =
            ((const float4*)(Q + ((size_t)bh * L_ + qt * 8) * DIM_))[tid];
    __syncthreads();

    if (tid < 125) {
        const int k0 = tid * 8;
        const float* KTb = KT + (size_t)bh * DIM_ * L_;
        float acc[8][8];
#pragma unroll
        for (int r = 0; r < 8; r++)
#pragma unroll
            for (int k = 0; k < 8; k++) acc[r][k] = 0.f;

        for (int d4 = 0; d4 < 9; d4++) {
            float4 q4[8];
#pragma unroll
            for (int r = 0; r < 8; r++) q4[r] = *(const float4*)&qs[r][d4 * 4];
            const float* kp0 = KTb + (size_t)(d4 * 4) * L_ + k0;
#pragma unroll
            for (int j = 0; j < 4; j++) {
                const float* kp = kp0 + (size_t)j * L_;
                float4 ka = *(const float4*)kp;
                float4 kb = *(const float4*)(kp + 4);
#pragma unroll
                for (int r = 0; r < 8; r++) {
                    float qv = (j == 0) ? q4[r].x : (j == 1) ? q4[r].y
                             : (j == 2) ? q4[r].z : q4[r].w;
                    acc[r][0] += qv * ka.x; acc[r][1] += qv * ka.y;
                    acc[r][2] += qv * ka.z; acc[r][3] += qv * ka.w;
                    acc[r][4] += qv * kb.x; acc[r][5] += qv * kb.y;
                    acc[r][6] += qv * kb.z; acc[r][7] += qv * kb.w;
                }
            }
        }
#pragma unroll
        for (int r = 0; r < 8; r++) {
            *(float4*)&st[r][k0] =
                make_float4(acc[r][0], acc[r][1], acc[r][2], acc[r][3]);
            *(float4*)&st[r][k0 + 4] =
                make_float4(acc[r][4], acc[r][5], acc[r][6], acc[r][7]);
        }
    }
    __syncthreads();

    // measure: 16 lanes per query (8 queries x 16 = 128 threads)
    const int r = tid >> 4;
    const int lane = tid & 15;
    const int l = qt * 8 + r;
    const int* ik = index_key + l * KS_;
    float mx = -1e30f, sm = 0.f;
    for (int s = lane; s < KS_; s += 16) {
        float v = st[r][ik[s]];
        mx = fmaxf(mx, v);
        sm += v;
    }
#pragma unroll
    for (int off = 8; off; off >>= 1) {
        mx = fmaxf(mx, __shfl_xor(mx, off));
        sm += __shfl_xor(sm, off);
    }
    if (lane == 0) measure[bh * L_ + l] = mx - sm * (1.0f / (float)L_);
}

// ---------------------------------------------------------------------------
// K3-fallback: gather-based measure.
// ---------------------------------------------------------------------------
__global__ __launch_bounds__(256) void measure_kernel(
    const float* __restrict__ Q, const float* __restrict__ K,
    const int* __restrict__ index_key, float* __restrict__ measure)
{
    const int w = threadIdx.x >> 6;
    const int lane = threadIdx.x & 63;
    const int wid = blockIdx.x * 4 + w;
    const int bh = wid / L_;
    const int l = wid % L_;

    const float4* qp = (const float4*)(Q + ((size_t)bh * L_ + l) * DIM_);
    float4 q[9];
#pragma unroll
    for (int i = 0; i < 9; i++) q[i] = qp[i];

    const int* ik = index_key + l * KS_;
    const float* Kb = K + (size_t)bh * L_ * DIM_;

    float mx = -1e30f, sm = 0.f;
#pragma unroll
    for (int s = lane; s < KS_; s += 64) {
        int kidx = ik[s];
        const float4* k4 = (const float4*)(Kb + (size_t)kidx * DIM_);
        float acc = 0.f;
#pragma unroll
        for (int i = 0; i < 9; i++) acc += dot4(q[i], k4[i]);
        mx = fmaxf(mx, acc);
        sm += acc;
    }
#pragma unroll
    for (int off = 32; off; off >>= 1) {
        mx = fmaxf(mx, __shfl_xor(mx, off));
        sm += __shfl_xor(sm, off);
    }
    if (lane == 0) measure[wid] = mx - sm * (1.0f / (float)L_);
}

// ---------------------------------------------------------------------------
// K4+K2 merged: top-NQ rank-based (blocks 0..63) + Vmean (blocks 64..79).
// ---------------------------------------------------------------------------
__global__ __launch_bounds__(256) void topk_vmean_kernel(
    const float* __restrict__ measure, int* __restrict__ qlist,
    int* __restrict__ slot_map, const float* __restrict__ V,
    float* __restrict__ Vmean)
{
    if (blockIdx.x < BH_ * 4) {
        const int bh = blockIdx.x >> 2;
        const int quarter = blockIdx.x & 3;
        __shared__ float m[L_];
        for (int i = threadIdx.x; i < L_; i += 256) m[i] = measure[bh * L_ + i];
        __syncthreads();
        const int i = quarter * 250 + threadIdx.x;
        if (threadIdx.x < 250) {
            float mi = m[i];
            int rank = 0;
            for (int j = 0; j < L_; j++) {
                float mj = m[j];
                rank += (mj > mi) || (mj == mi && j < i);
            }
            if (rank < NQ_) qlist[bh * NQ_ + rank] = i;
            slot_map[bh * L_ + i] = (rank < NQ_) ? rank : -1;
        }
    } else {
        const int bh = blockIdx.x - BH_ * 4;
        const int tid = threadIdx.x;
        __shared__ float red2[7][DIM_];
        if (tid < 252) {
            int gq = tid / DIM_, d = tid % DIM_;
            const float* basep = V + (size_t)bh * L_ * DIM_;
            float s = 0.f;
            for (int l = gq; l < L_; l += 7) s += basep[l * DIM_ + d];
            red2[gq][d] = s;
        }
        __syncthreads();
        if (tid < DIM_) {
            float s = 0.f;
#pragma unroll
            for (int gq = 0; gq < 7; gq++) s += red2[gq][tid];
            Vmean[bh * DIM_ + tid] = s * (1.0f / L_);
        }
    }
}

// ---------------------------------------------------------------------------
// K6 v3: attention partials, 2 query-slots per thread (block 128, 125
// active). grid BH_*nchunk.
// ---------------------------------------------------------------------------
__global__ __launch_bounds__(128) void attn_part3_kernel(
    const float* __restrict__ Q, const float* __restrict__ K,
    const float* __restrict__ V, const int* __restrict__ qlist,
    float* __restrict__ part, int nchunk, int chunk_len)
{
    __shared__ float Ks[MAXCL_ * DIM_];
    __shared__ float Vs[MAXCL_ * DIM_];
    const int bh = blockIdx.x / nchunk;
    const int chunk = blockIdx.x % nchunk;
    const int tid = threadIdx.x;
    const int k0 = chunk * chunk_len;

    {
        const float4* Ksrc = (const float4*)(K + ((size_t)bh * L_ + k0) * DIM_);
        const float4* Vsrc = (const float4*)(V + ((size_t)bh * L_ + k0) * DIM_);
        const int nf4 = chunk_len * (DIM_ / 4);
        for (int i = tid; i < nf4; i += 128) {
            ((float4*)Ks)[i] = Ksrc[i];
            ((float4*)Vs)[i] = Vsrc[i];
        }
    }
    __syncthreads();

    if (tid >= 125) return;
    const int s0 = tid * 2;

    const int qidx0 = qlist[bh * NQ_ + s0];
    const int qidx1 = qlist[bh * NQ_ + s0 + 1];
    const float4* qp0 = (const float4*)(Q + ((size_t)bh * L_ + qidx0) * DIM_);
    const float4* qp1 = (const float4*)(Q + ((size_t)bh * L_ + qidx1) * DIM_);
    float4 q0[9], q1[9];
#pragma unroll
    for (int i = 0; i < 9; i++) { q0[i] = qp0[i]; q1[i] = qp1[i]; }

    const float scale = (float)(1.0 / 6.0);
    float4 acc0[9], acc1[9];
#pragma unroll
    for (int i = 0; i < 9; i++) {
        acc0[i] = make_float4(0.f, 0.f, 0.f, 0.f);
        acc1[i] = make_float4(0.f, 0.f, 0.f, 0.f);
    }
    float sum0 = 0.f, sum1 = 0.f;

    for (int j = 0; j < chunk_len; j++) {
        const float4* kp = (const float4*)(Ks + j * DIM_);   // broadcast
        float sa = 0.f, sb = 0.f;
#pragma unroll
        for (int i = 0; i < 9; i++) {
            float4 kf = kp[i];
            sa += dot4(q0[i], kf);
            sb += dot4(q1[i], kf);
        }
        float e0 = __expf(sa * scale);
        float e1 = __expf(sb * scale);
        sum0 += e0; sum1 += e1;
        const float4* vp = (const float4*)(Vs + j * DIM_);   // broadcast
#pragma unroll
        for (int i = 0; i < 9; i++) {
            float4 vv = vp[i];
            acc0[i].x += e0 * vv.x; acc0[i].y += e0 * vv.y;
            acc0[i].z += e0 * vv.z; acc0[i].w += e0 * vv.w;
            acc1[i].x += e1 * vv.x; acc1[i].y += e1 * vv.y;
            acc1[i].z += e1 * vv.z; acc1[i].w += e1 * vv.w;
        }
    }

    float* p0 = part + ((size_t)(bh * NQ_ + s0) * nchunk + chunk) * PSTRIDE_;
    float* p1 = part + ((size_t)(bh * NQ_ + s0 + 1) * nchunk + chunk) * PSTRIDE_;
#pragma unroll
    for (int i = 0; i < 9; i++) {
        ((float4*)p0)[i] = acc0[i];
        ((float4*)p1)[i] = acc1[i];
    }
    p0[DIM_] = sum0;
    p1[DIM_] = sum1;
}

// ---------------------------------------------------------------------------
// K7+K8 fused: combine partials (or Vmean) + residual + LN1. grid 2000.
// ---------------------------------------------------------------------------
__global__ __launch_bounds__(320) void combine_ln1_kernel(
    const float* __restrict__ x, const float* __restrict__ part,
    const int* __restrict__ slot_map, const float* __restrict__ Vmean,
    const float* __restrict__ g, const float* __restrict__ bb,
    float* __restrict__ h1, int nchunk)
{
    const int row = blockIdx.x;          // 0..B_*L_-1
    const int b = row / L_, l = row % L_;
    const int tid = threadIdx.x;
    __shared__ float psum[5], pssq[5];

    float y = 0.f;
    if (tid < D_) {
        const int h = tid / DIM_, d = tid % DIM_;
        const int bh = b * H_ + h;
        const int slot = slot_map[bh * L_ + l];
        float v;
        if (slot < 0) {
            v = Vmean[bh * DIM_ + d];
        } else {
            const float* p = part + (size_t)(bh * NQ_ + slot) * nchunk * PSTRIDE_;
            float a = 0.f, s = 0.f;
            for (int c = 0; c < nchunk; c++) {
                a += p[c * PSTRIDE_ + d];
                s += p[c * PSTRIDE_ + DIM_];
            }
            v = a / s;
        }
        y = x[(size_t)row * D_ + tid] + v;
    }

    float s1 = y, s2 = y * y;
#pragma unroll
    for (int off = 32; off; off >>= 1) {
        s1 += __shfl_xor(s1, off);
        s2 += __shfl_xor(s2, off);
    }
    const int w = tid >> 6, lane = tid & 63;
    if (lane == 0) { psum[w] = s1; pssq[w] = s2; }
    __syncthreads();
    float ts = 0.f, tq = 0.f;
#pragma unroll
    for (int i = 0; i < 5; i++) { ts += psum[i]; tq += pssq[i]; }
    float mu = ts * (1.0f / D_);
    float var = tq * (1.0f / D_) - mu * mu;
    float rstd = rsqrtf(var + EPS_);
    if (tid < D_)
        h1[(size_t)row * D_ + tid] = (y - mu) * rstd * g[tid] + bb[tid];
}

// ---------------------------------------------------------------------------
// K9a: FFN GEMM1: f1 = gelu(h1 @ W1T + b1). 32x64 tiles, grid 567,
// block 256, thread = 2 rows x 4 cols, full k=288 staged in LDS.
// ---------------------------------------------------------------------------
__global__ __launch_bounds__(256) void ffn_gemm1_kernel(
    const float* __restrict__ h1, const float* __restrict__ W1T,
    const float* __restrict__ b1, float* __restrict__ f1)
{
    __shared__ float hsT[D_][34];       // [k][row], pad 34 -> 39168 B
    const int bx = blockIdx.x / 9;
    const int tile_c = (blockIdx.x % 9) * 64;
    const int base = bx * 32;
    const int tid = threadIdx.x;

    for (int idx = tid; idx < 32 * 72; idx += 256) {
        int row = idx / 72, k4 = idx % 72;
        int gr = base + row; if (gr > B_ * L_ - 1) gr = B_ * L_ - 1;
        float4 v = *(const float4*)(h1 + (size_t)gr * D_ + 4 * k4);
        hsT[4 * k4 + 0][row] = v.x;
        hsT[4 * k4 + 1][row] = v.y;
        hsT[4 * k4 + 2][row] = v.z;
        hsT[4 * k4 + 3][row] = v.w;
    }
    __syncthreads();

    const int cg = tid & 15, rg = tid >> 4;   // cg fastest -> coalesced weights
    const int c = tile_c + 4 * cg;
    const int r0 = 2 * rg;

    float4 bias = *(const float4*)(b1 + c);
    float a00 = bias.x, a01 = bias.y, a02 = bias.z, a03 = bias.w;
    float a10 = bias.x, a11 = bias.y, a12 = bias.z, a13 = bias.w;

    const float* wp = W1T + c;
    for (int k = 0; k < D_; k++) {
        float4 w = *(const float4*)wp; wp += DFF_;
        float x0 = hsT[k][r0], x1 = hsT[k][r0 + 1];
        a00 += w.x * x0; a01 += w.y * x0; a02 += w.z * x0; a03 += w.w * x0;
        a10 += w.x * x1; a11 += w.y * x1; a12 += w.z * x1; a13 += w.w * x1;
    }

    int row0 = base + r0;
    if (row0 < B_ * L_) {
        float4 y0 = make_float4(gelu_exact(a00), gelu_exact(a01),
                                gelu_exact(a02), gelu_exact(a03));
        *(float4*)(f1 + (size_t)row0 * DFF_ + c) = y0;
    }
    if (row0 + 1 < B_ * L_) {
        float4 y1 = make_float4(gelu_exact(a10), gelu_exact(a11),
                                gelu_exact(a12), gelu_exact(a13));
        *(float4*)(f1 + (size_t)(row0 + 1) * DFF_ + c) = y1;
    }
}

// ---------------------------------------------------------------------------
// K9b: FFN GEMM2 + residual + LN2: out = LN(gelu(f1 @ W2T + b2) + h1).
// TM=8 full-width rows, block 576 = 2 k-groups x (4 rg x 72 cg), grid 250.
// ---------------------------------------------------------------------------
__global__ __launch_bounds__(576) void ffn_gemm2_kernel(
    const float* __restrict__ f1, const float* __restrict__ h1,
    const float* __restrict__ W2T, const float* __restrict__ b2,
    const float* __restrict__ g, const float* __restrict__ bb,
    float* __restrict__ out)
{
    __shared__ float fsT[DFF_][10];     // [k][row], pad 10 -> 23040 B
    __shared__ float hs[8][D_];         // residual, 9216 B
    __shared__ float red[8 * D_];       // kg1 partials, 9216 B
    __shared__ float ys[8][D_];         // 9216 B
    const int base = blockIdx.x * 8;
    const int tid = threadIdx.x;

    for (int idx = tid; idx < 8 * 144; idx += 576) {
        int row = idx / 144, k4 = idx % 144;
        float4 v = *(const float4*)(f1 + (size_t)(base + row) * DFF_ + 4 * k4);
        fsT[4 * k4 + 0][row] = v.x;
        fsT[4 * k4 + 1][row] = v.y;
        fsT[4 * k4 + 2][row] = v.z;
        fsT[4 * k4 + 3][row] = v.w;
    }
    {
        int row = tid / 72, k4 = tid % 72;
        ((float4*)&hs[row][0])[k4] =
            *(const float4*)(h1 + (size_t)(base + row) * D_ + 4 * k4);
    }
    __syncthreads();

    const int kg = tid / 288;            // 0,1
    const int t2 = tid - kg * 288;
    const int rg = t2 / 72;              // 0..3
    const int cg = t2 - rg * 72;         // cg fastest within rg run
    const int c = 4 * cg;
    const int r0 = 2 * rg;

    float a00, a01, a02, a03, a10, a11, a12, a13;
    if (kg == 0) {
        float4 bias = *(const float4*)(b2 + c);
        a00 = bias.x; a01 = bias.y; a02 = bias.z; a03 = bias.w;
        a10 = bias.x; a11 = bias.y; a12 = bias.z; a13 = bias.w;
    } else {
        a00 = a01 = a02 = a03 = a10 = a11 = a12 = a13 = 0.f;
    }

    const int kbeg = kg * 288;
    const float* wp = W2T + (size_t)kbeg * D_ + c;
    for (int kk = 0; kk < 288; kk++) {
        float4 w = *(const float4*)wp; wp += D_;
        int k = kbeg + kk;
        float x0 = fsT[k][r0], x1 = fsT[k][r0 + 1];
        a00 += w.x * x0; a01 += w.y * x0; a02 += w.z * x0; a03 += w.w * x0;
        a10 += w.x * x1; a11 += w.y * x1; a12 += w.z * x1; a13 += w.w * x1;
    }

    if (kg == 1) {
        *(float4*)&red[r0 * D_ + c] = make_float4(a00, a01, a02, a03);
        *(float4*)&red[(r0 + 1) * D_ + c] = make_float4(a10, a11, a12, a13);
    }
    __syncthreads();
    if (kg == 0) {
        float4 o0 = *(const float4*)&red[r0 * D_ + c];
        float4 o1 = *(const float4*)&red[(r0 + 1) * D_ + c];
        float4 h0 = *(const float4*)&hs[r0][c];
        float4 h1v = *(const float4*)&hs[r0 + 1][c];
        float4 y0 = make_float4(gelu_exact(a00 + o0.x) + h0.x,
                                gelu_exact(a01 + o0.y) + h0.y,
                                gelu_exact(a02 + o0.z) + h0.z,
                                gelu_exact(a03 + o0.w) + h0.w);
        float4 y1 = make_float4(gelu_exact(a10 + o1.x) + h1v.x,
                                gelu_exact(a11 + o1.y) + h1v.y,
                                gelu_exact(a12 + o1.z) + h1v.z,
                                gelu_exact(a13 + o1.w) + h1v.w);
        *(float4*)&ys[r0][c] = y0;
        *(float4*)&ys[r0 + 1][c] = y1;
    }
    __syncthreads();

    // LN2: waves 0..7, one row each (wave 8 idle)
    const int w = tid >> 6;
    const int lane = tid & 63;
    if (w < 8) {
        const int r = w;
        float s = 0.f, ss = 0.f;
#pragma unroll
        for (int i = 0; i < 5; i++) {
            int j = lane + i * 64;
            if (j < D_) { float yv = ys[r][j]; s += yv; ss += yv * yv; }
        }
#pragma unroll
        for (int off = 32; off; off >>= 1) {
            s += __shfl_xor(s, off);
            ss += __shfl_xor(ss, off);
        }
        float mu = s * (1.0f / D_);
        float var = ss * (1.0f / D_) - mu * mu;
        float rstd = rsqrtf(var + EPS_);
        int row = base + r;
#pragma unroll
        for (int i = 0; i < 5; i++) {
            int j = lane + i * 64;
            if (j < D_)
                out[(size_t)row * D_ + j] = (ys[r][j] - mu) * rstd * g[j] + bb[j];
        }
    }
}

// ---------------------------------------------------------------------------
// K9-fallback: FFN layer 1, 3 cols/thread. grid 250, block 192.
// ---------------------------------------------------------------------------
__global__ __launch_bounds__(192) void ffn1_kernel(
    const float* __restrict__ h1,
    const float* __restrict__ W1, const float* __restrict__ b1,
    float* __restrict__ f1)
{
    constexpr int R = 8;
    __shared__ float hs[R][D_];
    const int base = blockIdx.x * R;
    const int tid = threadIdx.x;

    const float4* hsrc = (const float4*)(h1 + (size_t)base * D_);
    float4* hdst = (float4*)&hs[0][0];
    for (int i = tid; i < R * D_ / 4; i += 192) hdst[i] = hsrc[i];
    __syncthreads();

    const int j0 = tid, j1 = tid + 192, j2 = tid + 384;
    const float4* w0 = (const float4*)(W1 + (size_t)j0 * D_);
    const float4* w1 = (const float4*)(W1 + (size_t)j1 * D_);
    const float4* w2 = (const float4*)(W1 + (size_t)j2 * D_);
    float a0[R], a1[R], a2[R];
    float bb0 = b1[j0], bb1 = b1[j1], bb2 = b1[j2];
#pragma unroll
    for (int r = 0; r < R; r++) { a0[r] = bb0; a1[r] = bb1; a2[r] = bb2; }

    for (int d4 = 0; d4 < D_ / 4; d4++) {
        float4 x0 = w0[d4], x1 = w1[d4], x2 = w2[d4];
#pragma unroll
        for (int r = 0; r < R; r++) {
            float4 hv = *(const float4*)&hs[r][d4 * 4];
            a0[r] += dot4(hv, x0);
            a1[r] += dot4(hv, x1);
            a2[r] += dot4(hv, x2);
        }
    }
#pragma unroll
    for (int r = 0; r < R; r++) {
        size_t rowo = (size_t)(base + r) * DFF_;
        f1[rowo + j0] = gelu_exact(a0[r]);
        f1[rowo + j1] = gelu_exact(a1[r]);
        f1[rowo + j2] = gelu_exact(a2[r]);
    }
}

// ---------------------------------------------------------------------------
// K10-fallback: FFN layer 2 + residual + LN2 (non-transposed).
// ---------------------------------------------------------------------------
__global__ __launch_bounds__(320) void ffn2_ln_kernel(
    const float* __restrict__ f1, const float* __restrict__ h1,
    const float* __restrict__ W2, const float* __restrict__ b2,
    const float* __restrict__ g, const float* __restrict__ bb,
    float* __restrict__ out)
{
    constexpr int R = 8;
    __shared__ float fs[R][DFF_];
    __shared__ float hs[R][D_];
    __shared__ float ys[R][D_];
    const int base = blockIdx.x * R;
    const int tid = threadIdx.x;

    const float4* fsrc = (const float4*)(f1 + (size_t)base * DFF_);
    float4* fdst = (float4*)&fs[0][0];
    for (int i = tid; i < R * DFF_ / 4; i += 320) fdst[i] = fsrc[i];
    const float4* hsrc = (const float4*)(h1 + (size_t)base * D_);
    float4* hdst = (float4*)&hs[0][0];
    for (int i = tid; i < R * D_ / 4; i += 320) hdst[i] = hsrc[i];
    __syncthreads();

    if (tid < D_) {
        const float4* w4 = (const float4*)(W2 + (size_t)tid * DFF_);
        float acc[R];
        float bias = b2[tid];
#pragma unroll
        for (int r = 0; r < R; r++) acc[r] = bias;
        for (int d4 = 0; d4 < DFF_ / 4; d4++) {
            float4 wv = w4[d4];
#pragma unroll
            for (int r = 0; r < R; r++) {
                float4 fv = *(const float4*)&fs[r][d4 * 4];
                acc[r] += dot4(fv, wv);
            }
        }
#pragma unroll
        for (int r = 0; r < R; r++) ys[r][tid] = gelu_exact(acc[r]) + hs[r][tid];
    }
    __syncthreads();

    const int w = tid >> 6;
    const int lane = tid & 63;
    for (int r = w; r < R; r += 5) {
        float s = 0.f, ss = 0.f;
#pragma unroll
        for (int i = 0; i < 5; i++) {
            int j = lane + i * 64;
            if (j < D_) { float y = ys[r][j]; s += y; ss += y * y; }
        }
#pragma unroll
        for (int off = 32; off; off >>= 1) {
            s += __shfl_xor(s, off);
            ss += __shfl_xor(ss, off);
        }
        float mu = s * (1.0f / D_);
        float var = ss * (1.0f / D_) - mu * mu;
        float rstd = rsqrtf(var + EPS_);
        int row = base + r;
#pragma unroll
        for (int i = 0; i < 5; i++) {
            int j = lane + i * 64;
            if (j < D_) out[(size_t)row * D_ + j] = (ys[r][j] - mu) * rstd * g[j] + bb[j];
        }
    }
}

// ---------------------------------------------------------------------------
extern "C" void kernel_launch(void* const* d_in, const int* in_sizes, int n_in,
                              void* d_out, int out_size, void* d_ws, size_t ws_size,
                              hipStream_t stream)
{
    const float* x         = (const float*)d_in[0];
    const int*   index_key = (const int*)  d_in[1];
    const float* Wq = (const float*)d_in[2];
    const float* bq = (const float*)d_in[3];
    const float* Wk = (const float*)d_in[4];
    const float* bk = (const float*)d_in[5];
    const float* Wv = (const float*)d_in[6];
    const float* bv = (const float*)d_in[7];
    const float* W1 = (const float*)d_in[8];
    const float* b1 = (const float*)d_in[9];
    const float* W2 = (const float*)d_in[10];
    const float* b2 = (const float*)d_in[11];
    const float* ln1_g = (const float*)d_in[12];
    const float* ln1_b = (const float*)d_in[13];
    const float* ln2_g = (const float*)d_in[14];
    const float* ln2_b = (const float*)d_in[15];
    float* out = (float*)d_out;

    // workspace carve (floats)
    float* Q        = (float*)d_ws;                      // 576000
    float* K        = Q + 576000;
    float* V        = K + 576000;
    float* Vmean    = V + 576000;                        // 576
    float* measure  = Vmean + 576;                       // 16000
    float* wtbuf    = measure + 16000;                   // 576000 (W1T/W2T live here)
    float* h1       = wtbuf + 576000;                    // 576000
    int*   qlist    = (int*)(h1 + 576000);               // 4000 ints
    int*   slot_map = qlist + 4000;                      // 16000 ints
    float* part     = (float*)(slot_map + 16000);        // 4,000,000
    float* f1       = part;                              // dead after combine_ln1
    float* KT       = part + 4000000;                    // 576,000

    // transposed QKV weights alias the part region (dead until attn_part):
    float* WqT = part;
    float* WkT = WqT + 82944;
    float* WvT = WkT + 82944;
    // FFN transposed weights live in wtbuf (written at stream start, read last):
    float* W1T = wtbuf;                                  // 165888 floats
    float* W2T = wtbuf + 165888;                         // 165888 floats

    const size_t kt_end = 2916576ull + 4000000ull + 576000ull;  // ~30 MB
    const bool   big    = ws_size >= kt_end * sizeof(float);
    const int    nchunk = big ? 25 : 8;
    const int    chunk_len = L_ / nchunk;

    if (big) {
        weights_prep_kernel<<<567, 256, 0, stream>>>(Wq, Wk, Wv, WqT, WkT, WvT,
                                                     W1, W2, W1T, W2T);
        qkvT4_kernel<<<250, 512, 0, stream>>>(x, WqT, WkT, WvT, bq, bk, bv,
                                              Q, K, V, KT);
        score_measure4_kernel<<<BH_ * 125, 128, 0, stream>>>(Q, KT, index_key, measure);
    } else {
        qkv_kernel<<<250, 320, 0, stream>>>(x, Wq, bq, Wk, bk, Wv, bv, Q, K, V);
        measure_kernel<<<4000, 256, 0, stream>>>(Q, K, index_key, measure);
    }
    topk_vmean_kernel<<<BH_ * 4 + BH_, 256, 0, stream>>>(measure, qlist, slot_map, V, Vmean);
    attn_part3_kernel<<<BH_ * nchunk, 128, 0, stream>>>(Q, K, V, qlist, part, nchunk, chunk_len);
    combine_ln1_kernel<<<B_ * L_, 320, 0, stream>>>(x, part, slot_map, Vmean,
                                                    ln1_g, ln1_b, h1, nchunk);
    if (big) {
        ffn_gemm1_kernel<<<567, 256, 0, stream>>>(h1, W1T, b1, f1);
        ffn_gemm2_kernel<<<250, 576, 0, stream>>>(f1, h1, W2T, b2,
                                                  ln2_g, ln2_b, out);
    } else {
        ffn1_kernel<<<250, 192, 0, stream>>>(h1, W1, b1, f1);
        ffn2_ln_kernel<<<250, 320, 0, stream>>>(f1, h1, W2, b2, ln2_g, ln2_b, out);
    }
}

// Round 6
// 297.031 us; speedup vs baseline: 1.0139x; 1.0139x over previous
//
#include <hip/hip_runtime.h>
#include <math.h>

// Problem constants
#define B_ 2
#define L_ 1000
#define D_ 288
#define H_ 8
#define DIM_ 36
#define DFF_ 576
#define KS_ 250
#define NQ_ 250
#define BH_ (B_ * H_)
#define EPS_ 1e-5f
#define PSTRIDE_ 40             // partial row: 36 acc + 1 sum, padded to 40
#define MAXCL_ 125              // max chunk_len (small-ws fallback)

__device__ __forceinline__ float gelu_exact(float x) {
    return 0.5f * x * (1.0f + erff(x * 0.70710678118654752f));
}

__device__ __forceinline__ float dot4(float4 a, float4 b) {
    return a.x * b.x + a.y * b.y + a.z * b.z + a.w * b.w;
}

// ---------------------------------------------------------------------------
// K0: merged weight prep: QKV transpose (blocks 0..242) + FFN transpose
// (blocks 243..566). One launch at stream start.
// ---------------------------------------------------------------------------
__global__ __launch_bounds__(256) void weights_prep_kernel(
    const float* __restrict__ Wq, const float* __restrict__ Wk,
    const float* __restrict__ Wv,
    float* __restrict__ WqT, float* __restrict__ WkT, float* __restrict__ WvT,
    const float* __restrict__ W1, const float* __restrict__ W2,
    float* __restrict__ W1T, float* __restrict__ W2T)
{
    __shared__ float tile[32][33];
    const int tx = threadIdx.x & 31, ty = threadIdx.x >> 5;
    if (blockIdx.x < 243) {
        const int m = blockIdx.x / 81;
        const int t = blockIdx.x % 81;
        const float* src = (m == 0) ? Wq : (m == 1) ? Wk : Wv;
        float* dst = (m == 0) ? WqT : (m == 1) ? WkT : WvT;
        const int ty0 = (t / 9) * 32, tx0 = (t % 9) * 32;
#pragma unroll
        for (int i = 0; i < 4; i++)
            tile[ty + 8 * i][tx] = src[(size_t)(ty0 + ty + 8 * i) * D_ + tx0 + tx];
        __syncthreads();
#pragma unroll
        for (int i = 0; i < 4; i++)
            dst[(size_t)(tx0 + ty + 8 * i) * D_ + ty0 + tx] = tile[tx][ty + 8 * i];
    } else {
        int t = blockIdx.x - 243;
        const float* src; float* dst; int Rr, Cc, ntx;
        if (t < 162) { src = W1; dst = W1T; Rr = DFF_; Cc = D_; ntx = 9; }
        else { t -= 162; src = W2; dst = W2T; Rr = D_; Cc = DFF_; ntx = 18; }
        const int ty0 = (t / ntx) * 32, tx0 = (t % ntx) * 32;
#pragma unroll
        for (int i = 0; i < 4; i++)
            tile[ty + 8 * i][tx] = src[(size_t)(ty0 + ty + 8 * i) * Cc + tx0 + tx];
        __syncthreads();
#pragma unroll
        for (int i = 0; i < 4; i++)
            dst[(size_t)(tx0 + ty + 8 * i) * Rr + ty0 + tx] = tile[tx][ty + 8 * i];
    }
}

// ---------------------------------------------------------------------------
// K1 v4b: QKV, R=8 rows/block, 249 MB weight L2 traffic. grid 250,
// block 512: 432 active = 216 col-groups x 2 k-groups of 144.
// __launch_bounds__(512, 2): min 2 waves/EU -> VGPR budget 256 (R5's
// unspecified bound let the backend cap at 32 VGPR -> no accumulator
// residency, no load pipelining, 44.6us latency-bound; VALUBusy 16.5%).
// ---------------------------------------------------------------------------
__global__ __launch_bounds__(512, 2) void qkvT4_kernel(
    const float* __restrict__ x,
    const float* __restrict__ WqT, const float* __restrict__ WkT,
    const float* __restrict__ WvT,
    const float* __restrict__ bq, const float* __restrict__ bk,
    const float* __restrict__ bv,
    float* __restrict__ Q, float* __restrict__ K, float* __restrict__ V,
    float* __restrict__ KT)
{
    __shared__ float xsT[D_][8];        // [k][r]  9216 B
    __shared__ float red[6912];         // kg1 partials 27648 B
    const int base = blockIdx.x * 8;
    const int tid = threadIdx.x;

    for (int idx = tid; idx < 8 * D_; idx += 512) {
        int r = idx / D_, k = idx % D_;
        xsT[k][r] = x[(size_t)(base + r) * D_ + k];
    }
    __syncthreads();

    const int kg = tid / 216;           // 0 or 1 (tid < 432)
    const int ct = tid - kg * 216;      // 0..215
    const bool active = tid < 432;

    float a[4][8];
    int m = 0, c = 0;
    if (active) {
        const int gcol = 4 * ct;              // 0..863
        m = gcol / D_;
        c = gcol - m * D_;
        const float* WT = (m == 0) ? WqT : (m == 1) ? WkT : WvT;
        const float* bias = (m == 0) ? bq : (m == 1) ? bk : bv;
#pragma unroll
        for (int j = 0; j < 4; j++) {
            float bv2 = (kg == 0) ? bias[c + j] : 0.f;
#pragma unroll
            for (int r = 0; r < 8; r++) a[j][r] = bv2;
        }
        const int kbeg = kg * 144;
        for (int k = kbeg; k < kbeg + 144; k++) {
            float4 w = *(const float4*)(WT + (size_t)k * D_ + c);
            float4 x0 = *(const float4*)&xsT[k][0];   // broadcast
            float4 x1 = *(const float4*)&xsT[k][4];   // broadcast
            a[0][0] += w.x * x0.x; a[0][1] += w.x * x0.y; a[0][2] += w.x * x0.z; a[0][3] += w.x * x0.w;
            a[0][4] += w.x * x1.x; a[0][5] += w.x * x1.y; a[0][6] += w.x * x1.z; a[0][7] += w.x * x1.w;
            a[1][0] += w.y * x0.x; a[1][1] += w.y * x0.y; a[1][2] += w.y * x0.z; a[1][3] += w.y * x0.w;
            a[1][4] += w.y * x1.x; a[1][5] += w.y * x1.y; a[1][6] += w.y * x1.z; a[1][7] += w.y * x1.w;
            a[2][0] += w.z * x0.x; a[2][1] += w.z * x0.y; a[2][2] += w.z * x0.z; a[2][3] += w.z * x0.w;
            a[2][4] += w.z * x1.x; a[2][5] += w.z * x1.y; a[2][6] += w.z * x1.z; a[2][7] += w.z * x1.w;
            a[3][0] += w.w * x0.x; a[3][1] += w.w * x0.y; a[3][2] += w.w * x0.z; a[3][3] += w.w * x0.w;
            a[3][4] += w.w * x1.x; a[3][5] += w.w * x1.y; a[3][6] += w.w * x1.z; a[3][7] += w.w * x1.w;
        }
        if (kg == 1) {
#pragma unroll
            for (int j = 0; j < 4; j++) {
                *(float4*)&red[(j * 216 + ct) * 8 + 0] =
                    make_float4(a[j][0], a[j][1], a[j][2], a[j][3]);
                *(float4*)&red[(j * 216 + ct) * 8 + 4] =
                    make_float4(a[j][4], a[j][5], a[j][6], a[j][7]);
            }
        }
    }
    __syncthreads();

    if (active && kg == 0) {
        const int bb_ = base / L_;             // block never spans b boundary
        const int l0 = base % L_;
        float* outp = (m == 0) ? Q : (m == 1) ? K : V;
#pragma unroll
        for (int j = 0; j < 4; j++) {
            float4 o0 = *(const float4*)&red[(j * 216 + ct) * 8 + 0];
            float4 o1 = *(const float4*)&red[(j * 216 + ct) * 8 + 4];
            a[j][0] += o0.x; a[j][1] += o0.y; a[j][2] += o0.z; a[j][3] += o0.w;
            a[j][4] += o1.x; a[j][5] += o1.y; a[j][6] += o1.z; a[j][7] += o1.w;
            int col = c + j;
            int h = col / DIM_, dd = col % DIM_;
#pragma unroll
            for (int r = 0; r < 8; r++) {
                int row = base + r;
                int b = row / L_, l = row % L_;
                outp[((size_t)(b * H_ + h) * L_ + l) * DIM_ + dd] = a[j][r];
            }
            if (m == 1) {
                float* kt = KT + ((size_t)(bb_ * H_ + h) * DIM_ + dd) * L_ + l0;
                *(float4*)kt = make_float4(a[j][0], a[j][1], a[j][2], a[j][3]);
                *(float4*)(kt + 4) = make_float4(a[j][4], a[j][5], a[j][6], a[j][7]);
            }
        }
    }
}

// ---------------------------------------------------------------------------
// K1-fallback: qkv with row-major weights (small-ws path, no KT).
// ---------------------------------------------------------------------------
__global__ __launch_bounds__(320) void qkv_kernel(
    const float* __restrict__ x,
    const float* __restrict__ Wq, const float* __restrict__ bq,
    const float* __restrict__ Wk, const float* __restrict__ bk,
    const float* __restrict__ Wv, const float* __restrict__ bv,
    float* __restrict__ Q, float* __restrict__ K, float* __restrict__ V)
{
    constexpr int R = 8;
    __shared__ float xs[R][D_];
    const int base = blockIdx.x * R;
    const int tid = threadIdx.x;

    const float4* xsrc = (const float4*)(x + (size_t)base * D_);
    float4* xdst = (float4*)&xs[0][0];
    for (int i = tid; i < R * D_ / 4; i += 320) xdst[i] = xsrc[i];
    __syncthreads();

    if (tid < D_) {
        const float4* wq4 = (const float4*)(Wq + (size_t)tid * D_);
        const float4* wk4 = (const float4*)(Wk + (size_t)tid * D_);
        const float4* wv4 = (const float4*)(Wv + (size_t)tid * D_);
        float aq[R], ak[R], av[R];
        float biasq = bq[tid], biask = bk[tid], biasv = bv[tid];
#pragma unroll
        for (int r = 0; r < R; r++) { aq[r] = biasq; ak[r] = biask; av[r] = biasv; }
        for (int d4 = 0; d4 < D_ / 4; d4++) {
            float4 wqv = wq4[d4], wkv = wk4[d4], wvv = wv4[d4];
#pragma unroll
            for (int r = 0; r < R; r++) {
                float4 hv = *(const float4*)&xs[r][d4 * 4];
                aq[r] += dot4(hv, wqv);
                ak[r] += dot4(hv, wkv);
                av[r] += dot4(hv, wvv);
            }
        }
        const int h = tid / DIM_, dd = tid % DIM_;
#pragma unroll
        for (int r = 0; r < R; r++) {
            int row = base + r;
            int b = row / L_, l = row % L_;
            size_t o = ((size_t)(b * H_ + h) * L_ + l) * DIM_ + dd;
            Q[o] = aq[r]; K[o] = ak[r]; V[o] = av[r];
        }
    }
}

// ---------------------------------------------------------------------------
// K3 v4: score+measure, 8 keys/thread (block 128, 125 active). grid 2000.
// ---------------------------------------------------------------------------
__global__ __launch_bounds__(128) void score_measure4_kernel(
    const float* __restrict__ Q, const float* __restrict__ KT,
    const int* __restrict__ index_key, float* __restrict__ measure)
{
    __shared__ float qs[8][DIM_];       // 1152 B
    __shared__ float st[8][1004];       // 32128 B
    const int bh = blockIdx.x / 125;
    const int qt = blockIdx.x % 125;
    const int tid = threadIdx.x;

    if (tid < 72)
        ((float4*)&qs[0][0])[tid] =
            ((const float4*)(Q + ((size_t)bh * L_ + qt * 8) * DIM_))[tid];
    __syncthreads();

    if (tid < 125) {
        const int k0 = tid * 8;
        const float* KTb = KT + (size_t)bh * DIM_ * L_;
        float acc[8][8];
#pragma unroll
        for (int r = 0; r < 8; r++)
#pragma unroll
            for (int k = 0; k < 8; k++) acc[r][k] = 0.f;

        for (int d4 = 0; d4 < 9; d4++) {
            float4 q4[8];
#pragma unroll
            for (int r = 0; r < 8; r++) q4[r] = *(const float4*)&qs[r][d4 * 4];
            const float* kp0 = KTb + (size_t)(d4 * 4) * L_ + k0;
#pragma unroll
            for (int j = 0; j < 4; j++) {
                const float* kp = kp0 + (size_t)j * L_;
                float4 ka = *(const float4*)kp;
                float4 kb = *(const float4*)(kp + 4);
#pragma unroll
                for (int r = 0; r < 8; r++) {
                    float qv = (j == 0) ? q4[r].x : (j == 1) ? q4[r].y
                             : (j == 2) ? q4[r].z : q4[r].w;
                    acc[r][0] += qv * ka.x; acc[r][1] += qv * ka.y;
                    acc[r][2] += qv * ka.z; acc[r][3] += qv * ka.w;
                    acc[r][4] += qv * kb.x; acc[r][5] += qv * kb.y;
                    acc[r][6] += qv * kb.z; acc[r][7] += qv * kb.w;
                }
            }
        }
#pragma unroll
        for (int r = 0; r < 8; r++) {
            *(float4*)&st[r][k0] =
                make_float4(acc[r][0], acc[r][1], acc[r][2], acc[r][3]);
            *(float4*)&st[r][k0 + 4] =
                make_float4(acc[r][4], acc[r][5], acc[r][6], acc[r][7]);
        }
    }
    __syncthreads();

    // measure: 16 lanes per query (8 queries x 16 = 128 threads)
    const int r = tid >> 4;
    const int lane = tid & 15;
    const int l = qt * 8 + r;
    const int* ik = index_key + l * KS_;
    float mx = -1e30f, sm = 0.f;
    for (int s = lane; s < KS_; s += 16) {
        float v = st[r][ik[s]];
        mx = fmaxf(mx, v);
        sm += v;
    }
#pragma unroll
    for (int off = 8; off; off >>= 1) {
        mx = fmaxf(mx, __shfl_xor(mx, off));
        sm += __shfl_xor(sm, off);
    }
    if (lane == 0) measure[bh * L_ + l] = mx - sm * (1.0f / (float)L_);
}

// ---------------------------------------------------------------------------
// K3-fallback: gather-based measure.
// ---------------------------------------------------------------------------
__global__ __launch_bounds__(256) void measure_kernel(
    const float* __restrict__ Q, const float* __restrict__ K,
    const int* __restrict__ index_key, float* __restrict__ measure)
{
    const int w = threadIdx.x >> 6;
    const int lane = threadIdx.x & 63;
    const int wid = blockIdx.x * 4 + w;
    const int bh = wid / L_;
    const int l = wid % L_;

    const float4* qp = (const float4*)(Q + ((size_t)bh * L_ + l) * DIM_);
    float4 q[9];
#pragma unroll
    for (int i = 0; i < 9; i++) q[i] = qp[i];

    const int* ik = index_key + l * KS_;
    const float* Kb = K + (size_t)bh * L_ * DIM_;

    float mx = -1e30f, sm = 0.f;
#pragma unroll
    for (int s = lane; s < KS_; s += 64) {
        int kidx = ik[s];
        const float4* k4 = (const float4*)(Kb + (size_t)kidx * DIM_);
        float acc = 0.f;
#pragma unroll
        for (int i = 0; i < 9; i++) acc += dot4(q[i], k4[i]);
        mx = fmaxf(mx, acc);
        sm += acc;
    }
#pragma unroll
    for (int off = 32; off; off >>= 1) {
        mx = fmaxf(mx, __shfl_xor(mx, off));
        sm += __shfl_xor(sm, off);
    }
    if (lane == 0) measure[wid] = mx - sm * (1.0f / (float)L_);
}

// ---------------------------------------------------------------------------
// K4+K2 merged: top-NQ rank-based (blocks 0..63) + Vmean (blocks 64..79).
// ---------------------------------------------------------------------------
__global__ __launch_bounds__(256) void topk_vmean_kernel(
    const float* __restrict__ measure, int* __restrict__ qlist,
    int* __restrict__ slot_map, const float* __restrict__ V,
    float* __restrict__ Vmean)
{
    if (blockIdx.x < BH_ * 4) {
        const int bh = blockIdx.x >> 2;
        const int quarter = blockIdx.x & 3;
        __shared__ float m[L_];
        for (int i = threadIdx.x; i < L_; i += 256) m[i] = measure[bh * L_ + i];
        __syncthreads();
        const int i = quarter * 250 + threadIdx.x;
        if (threadIdx.x < 250) {
            float mi = m[i];
            int rank = 0;
            for (int j = 0; j < L_; j++) {
                float mj = m[j];
                rank += (mj > mi) || (mj == mi && j < i);
            }
            if (rank < NQ_) qlist[bh * NQ_ + rank] = i;
            slot_map[bh * L_ + i] = (rank < NQ_) ? rank : -1;
        }
    } else {
        const int bh = blockIdx.x - BH_ * 4;
        const int tid = threadIdx.x;
        __shared__ float red2[7][DIM_];
        if (tid < 252) {
            int gq = tid / DIM_, d = tid % DIM_;
            const float* basep = V + (size_t)bh * L_ * DIM_;
            float s = 0.f;
            for (int l = gq; l < L_; l += 7) s += basep[l * DIM_ + d];
            red2[gq][d] = s;
        }
        __syncthreads();
        if (tid < DIM_) {
            float s = 0.f;
#pragma unroll
            for (int gq = 0; gq < 7; gq++) s += red2[gq][tid];
            Vmean[bh * DIM_ + tid] = s * (1.0f / L_);
        }
    }
}

// ---------------------------------------------------------------------------
// K6 v3: attention partials, 2 query-slots per thread (block 128, 125
// active). grid BH_*nchunk.
// ---------------------------------------------------------------------------
__global__ __launch_bounds__(128) void attn_part3_kernel(
    const float* __restrict__ Q, const float* __restrict__ K,
    const float* __restrict__ V, const int* __restrict__ qlist,
    float* __restrict__ part, int nchunk, int chunk_len)
{
    __shared__ float Ks[MAXCL_ * DIM_];
    __shared__ float Vs[MAXCL_ * DIM_];
    const int bh = blockIdx.x / nchunk;
    const int chunk = blockIdx.x % nchunk;
    const int tid = threadIdx.x;
    const int k0 = chunk * chunk_len;

    {
        const float4* Ksrc = (const float4*)(K + ((size_t)bh * L_ + k0) * DIM_);
        const float4* Vsrc = (const float4*)(V + ((size_t)bh * L_ + k0) * DIM_);
        const int nf4 = chunk_len * (DIM_ / 4);
        for (int i = tid; i < nf4; i += 128) {
            ((float4*)Ks)[i] = Ksrc[i];
            ((float4*)Vs)[i] = Vsrc[i];
        }
    }
    __syncthreads();

    if (tid >= 125) return;
    const int s0 = tid * 2;

    const int qidx0 = qlist[bh * NQ_ + s0];
    const int qidx1 = qlist[bh * NQ_ + s0 + 1];
    const float4* qp0 = (const float4*)(Q + ((size_t)bh * L_ + qidx0) * DIM_);
    const float4* qp1 = (const float4*)(Q + ((size_t)bh * L_ + qidx1) * DIM_);
    float4 q0[9], q1[9];
#pragma unroll
    for (int i = 0; i < 9; i++) { q0[i] = qp0[i]; q1[i] = qp1[i]; }

    const float scale = (float)(1.0 / 6.0);
    float4 acc0[9], acc1[9];
#pragma unroll
    for (int i = 0; i < 9; i++) {
        acc0[i] = make_float4(0.f, 0.f, 0.f, 0.f);
        acc1[i] = make_float4(0.f, 0.f, 0.f, 0.f);
    }
    float sum0 = 0.f, sum1 = 0.f;

    for (int j = 0; j < chunk_len; j++) {
        const float4* kp = (const float4*)(Ks + j * DIM_);   // broadcast
        float sa = 0.f, sb = 0.f;
#pragma unroll
        for (int i = 0; i < 9; i++) {
            float4 kf = kp[i];
            sa += dot4(q0[i], kf);
            sb += dot4(q1[i], kf);
        }
        float e0 = __expf(sa * scale);
        float e1 = __expf(sb * scale);
        sum0 += e0; sum1 += e1;
        const float4* vp = (const float4*)(Vs + j * DIM_);   // broadcast
#pragma unroll
        for (int i = 0; i < 9; i++) {
            float4 vv = vp[i];
            acc0[i].x += e0 * vv.x; acc0[i].y += e0 * vv.y;
            acc0[i].z += e0 * vv.z; acc0[i].w += e0 * vv.w;
            acc1[i].x += e1 * vv.x; acc1[i].y += e1 * vv.y;
            acc1[i].z += e1 * vv.z; acc1[i].w += e1 * vv.w;
        }
    }

    float* p0 = part + ((size_t)(bh * NQ_ + s0) * nchunk + chunk) * PSTRIDE_;
    float* p1 = part + ((size_t)(bh * NQ_ + s0 + 1) * nchunk + chunk) * PSTRIDE_;
#pragma unroll
    for (int i = 0; i < 9; i++) {
        ((float4*)p0)[i] = acc0[i];
        ((float4*)p1)[i] = acc1[i];
    }
    p0[DIM_] = sum0;
    p1[DIM_] = sum1;
}

// ---------------------------------------------------------------------------
// K7+K8 fused: combine partials (or Vmean) + residual + LN1. grid 2000.
// ---------------------------------------------------------------------------
__global__ __launch_bounds__(320) void combine_ln1_kernel(
    const float* __restrict__ x, const float* __restrict__ part,
    const int* __restrict__ slot_map, const float* __restrict__ Vmean,
    const float* __restrict__ g, const float* __restrict__ bb,
    float* __restrict__ h1, int nchunk)
{
    const int row = blockIdx.x;          // 0..B_*L_-1
    const int b = row / L_, l = row % L_;
    const int tid = threadIdx.x;
    __shared__ float psum[5], pssq[5];

    float y = 0.f;
    if (tid < D_) {
        const int h = tid / DIM_, d = tid % DIM_;
        const int bh = b * H_ + h;
        const int slot = slot_map[bh * L_ + l];
        float v;
        if (slot < 0) {
            v = Vmean[bh * DIM_ + d];
        } else {
            const float* p = part + (size_t)(bh * NQ_ + slot) * nchunk * PSTRIDE_;
            float a = 0.f, s = 0.f;
            for (int c = 0; c < nchunk; c++) {
                a += p[c * PSTRIDE_ + d];
                s += p[c * PSTRIDE_ + DIM_];
            }
            v = a / s;
        }
        y = x[(size_t)row * D_ + tid] + v;
    }

    float s1 = y, s2 = y * y;
#pragma unroll
    for (int off = 32; off; off >>= 1) {
        s1 += __shfl_xor(s1, off);
        s2 += __shfl_xor(s2, off);
    }
    const int w = tid >> 6, lane = tid & 63;
    if (lane == 0) { psum[w] = s1; pssq[w] = s2; }
    __syncthreads();
    float ts = 0.f, tq = 0.f;
#pragma unroll
    for (int i = 0; i < 5; i++) { ts += psum[i]; tq += pssq[i]; }
    float mu = ts * (1.0f / D_);
    float var = tq * (1.0f / D_) - mu * mu;
    float rstd = rsqrtf(var + EPS_);
    if (tid < D_)
        h1[(size_t)row * D_ + tid] = (y - mu) * rstd * g[tid] + bb[tid];
}

// ---------------------------------------------------------------------------
// K9a: FFN GEMM1: f1 = gelu(h1 @ W1T + b1). 32x64 tiles, grid 567,
// block 256, thread = 2 rows x 4 cols, full k=288 staged in LDS.
// ---------------------------------------------------------------------------
__global__ __launch_bounds__(256) void ffn_gemm1_kernel(
    const float* __restrict__ h1, const float* __restrict__ W1T,
    const float* __restrict__ b1, float* __restrict__ f1)
{
    __shared__ float hsT[D_][34];       // [k][row], pad 34 -> 39168 B
    const int bx = blockIdx.x / 9;
    const int tile_c = (blockIdx.x % 9) * 64;
    const int base = bx * 32;
    const int tid = threadIdx.x;

    for (int idx = tid; idx < 32 * 72; idx += 256) {
        int row = idx / 72, k4 = idx % 72;
        int gr = base + row; if (gr > B_ * L_ - 1) gr = B_ * L_ - 1;
        float4 v = *(const float4*)(h1 + (size_t)gr * D_ + 4 * k4);
        hsT[4 * k4 + 0][row] = v.x;
        hsT[4 * k4 + 1][row] = v.y;
        hsT[4 * k4 + 2][row] = v.z;
        hsT[4 * k4 + 3][row] = v.w;
    }
    __syncthreads();

    const int cg = tid & 15, rg = tid >> 4;   // cg fastest -> coalesced weights
    const int c = tile_c + 4 * cg;
    const int r0 = 2 * rg;

    float4 bias = *(const float4*)(b1 + c);
    float a00 = bias.x, a01 = bias.y, a02 = bias.z, a03 = bias.w;
    float a10 = bias.x, a11 = bias.y, a12 = bias.z, a13 = bias.w;

    const float* wp = W1T + c;
    for (int k = 0; k < D_; k++) {
        float4 w = *(const float4*)wp; wp += DFF_;
        float x0 = hsT[k][r0], x1 = hsT[k][r0 + 1];
        a00 += w.x * x0; a01 += w.y * x0; a02 += w.z * x0; a03 += w.w * x0;
        a10 += w.x * x1; a11 += w.y * x1; a12 += w.z * x1; a13 += w.w * x1;
    }

    int row0 = base + r0;
    if (row0 < B_ * L_) {
        float4 y0 = make_float4(gelu_exact(a00), gelu_exact(a01),
                                gelu_exact(a02), gelu_exact(a03));
        *(float4*)(f1 + (size_t)row0 * DFF_ + c) = y0;
    }
    if (row0 + 1 < B_ * L_) {
        float4 y1 = make_float4(gelu_exact(a10), gelu_exact(a11),
                                gelu_exact(a12), gelu_exact(a13));
        *(float4*)(f1 + (size_t)(row0 + 1) * DFF_ + c) = y1;
    }
}

// ---------------------------------------------------------------------------
// K9b: FFN GEMM2 + residual + LN2: out = LN(gelu(f1 @ W2T + b2) + h1).
// TM=8 full-width rows, block 576 = 2 k-groups x (4 rg x 72 cg), grid 250.
// ---------------------------------------------------------------------------
__global__ __launch_bounds__(576) void ffn_gemm2_kernel(
    const float* __restrict__ f1, const float* __restrict__ h1,
    const float* __restrict__ W2T, const float* __restrict__ b2,
    const float* __restrict__ g, const float* __restrict__ bb,
    float* __restrict__ out)
{
    __shared__ float fsT[DFF_][10];     // [k][row], pad 10 -> 23040 B
    __shared__ float hs[8][D_];         // residual, 9216 B
    __shared__ float red[8 * D_];       // kg1 partials, 9216 B
    __shared__ float ys[8][D_];         // 9216 B
    const int base = blockIdx.x * 8;
    const int tid = threadIdx.x;

    for (int idx = tid; idx < 8 * 144; idx += 576) {
        int row = idx / 144, k4 = idx % 144;
        float4 v = *(const float4*)(f1 + (size_t)(base + row) * DFF_ + 4 * k4);
        fsT[4 * k4 + 0][row] = v.x;
        fsT[4 * k4 + 1][row] = v.y;
        fsT[4 * k4 + 2][row] = v.z;
        fsT[4 * k4 + 3][row] = v.w;
    }
    {
        int row = tid / 72, k4 = tid % 72;
        ((float4*)&hs[row][0])[k4] =
            *(const float4*)(h1 + (size_t)(base + row) * D_ + 4 * k4);
    }
    __syncthreads();

    const int kg = tid / 288;            // 0,1
    const int t2 = tid - kg * 288;
    const int rg = t2 / 72;              // 0..3
    const int cg = t2 - rg * 72;         // cg fastest within rg run
    const int c = 4 * cg;
    const int r0 = 2 * rg;

    float a00, a01, a02, a03, a10, a11, a12, a13;
    if (kg == 0) {
        float4 bias = *(const float4*)(b2 + c);
        a00 = bias.x; a01 = bias.y; a02 = bias.z; a03 = bias.w;
        a10 = bias.x; a11 = bias.y; a12 = bias.z; a13 = bias.w;
    } else {
        a00 = a01 = a02 = a03 = a10 = a11 = a12 = a13 = 0.f;
    }

    const int kbeg = kg * 288;
    const float* wp = W2T + (size_t)kbeg * D_ + c;
    for (int kk = 0; kk < 288; kk++) {
        float4 w = *(const float4*)wp; wp += D_;
        int k = kbeg + kk;
        float x0 = fsT[k][r0], x1 = fsT[k][r0 + 1];
        a00 += w.x * x0; a01 += w.y * x0; a02 += w.z * x0; a03 += w.w * x0;
        a10 += w.x * x1; a11 += w.y * x1; a12 += w.z * x1; a13 += w.w * x1;
    }

    if (kg == 1) {
        *(float4*)&red[r0 * D_ + c] = make_float4(a00, a01, a02, a03);
        *(float4*)&red[(r0 + 1) * D_ + c] = make_float4(a10, a11, a12, a13);
    }
    __syncthreads();
    if (kg == 0) {
        float4 o0 = *(const float4*)&red[r0 * D_ + c];
        float4 o1 = *(const float4*)&red[(r0 + 1) * D_ + c];
        float4 h0 = *(const float4*)&hs[r0][c];
        float4 h1v = *(const float4*)&hs[r0 + 1][c];
        float4 y0 = make_float4(gelu_exact(a00 + o0.x) + h0.x,
                                gelu_exact(a01 + o0.y) + h0.y,
                                gelu_exact(a02 + o0.z) + h0.z,
                                gelu_exact(a03 + o0.w) + h0.w);
        float4 y1 = make_float4(gelu_exact(a10 + o1.x) + h1v.x,
                                gelu_exact(a11 + o1.y) + h1v.y,
                                gelu_exact(a12 + o1.z) + h1v.z,
                                gelu_exact(a13 + o1.w) + h1v.w);
        *(float4*)&ys[r0][c] = y0;
        *(float4*)&ys[r0 + 1][c] = y1;
    }
    __syncthreads();

    // LN2: waves 0..7, one row each (wave 8 idle)
    const int w = tid >> 6;
    const int lane = tid & 63;
    if (w < 8) {
        const int r = w;
        float s = 0.f, ss = 0.f;
#pragma unroll
        for (int i = 0; i < 5; i++) {
            int j = lane + i * 64;
            if (j < D_) { float yv = ys[r][j]; s += yv; ss += yv * yv; }
        }
#pragma unroll
        for (int off = 32; off; off >>= 1) {
            s += __shfl_xor(s, off);
            ss += __shfl_xor(ss, off);
        }
        float mu = s * (1.0f / D_);
        float var = ss * (1.0f / D_) - mu * mu;
        float rstd = rsqrtf(var + EPS_);
        int row = base + r;
#pragma unroll
        for (int i = 0; i < 5; i++) {
            int j = lane + i * 64;
            if (j < D_)
                out[(size_t)row * D_ + j] = (ys[r][j] - mu) * rstd * g[j] + bb[j];
        }
    }
}

// ---------------------------------------------------------------------------
// K9-fallback: FFN layer 1, 3 cols/thread. grid 250, block 192.
// ---------------------------------------------------------------------------
__global__ __launch_bounds__(192) void ffn1_kernel(
    const float* __restrict__ h1,
    const float* __restrict__ W1, const float* __restrict__ b1,
    float* __restrict__ f1)
{
    constexpr int R = 8;
    __shared__ float hs[R][D_];
    const int base = blockIdx.x * R;
    const int tid = threadIdx.x;

    const float4* hsrc = (const float4*)(h1 + (size_t)base * D_);
    float4* hdst = (float4*)&hs[0][0];
    for (int i = tid; i < R * D_ / 4; i += 192) hdst[i] = hsrc[i];
    __syncthreads();

    const int j0 = tid, j1 = tid + 192, j2 = tid + 384;
    const float4* w0 = (const float4*)(W1 + (size_t)j0 * D_);
    const float4* w1 = (const float4*)(W1 + (size_t)j1 * D_);
    const float4* w2 = (const float4*)(W1 + (size_t)j2 * D_);
    float a0[R], a1[R], a2[R];
    float bb0 = b1[j0], bb1 = b1[j1], bb2 = b1[j2];
#pragma unroll
    for (int r = 0; r < R; r++) { a0[r] = bb0; a1[r] = bb1; a2[r] = bb2; }

    for (int d4 = 0; d4 < D_ / 4; d4++) {
        float4 x0 = w0[d4], x1 = w1[d4], x2 = w2[d4];
#pragma unroll
        for (int r = 0; r < R; r++) {
            float4 hv = *(const float4*)&hs[r][d4 * 4];
            a0[r] += dot4(hv, x0);
            a1[r] += dot4(hv, x1);
            a2[r] += dot4(hv, x2);
        }
    }
#pragma unroll
    for (int r = 0; r < R; r++) {
        size_t rowo = (size_t)(base + r) * DFF_;
        f1[rowo + j0] = gelu_exact(a0[r]);
        f1[rowo + j1] = gelu_exact(a1[r]);
        f1[rowo + j2] = gelu_exact(a2[r]);
    }
}

// ---------------------------------------------------------------------------
// K10-fallback: FFN layer 2 + residual + LN2 (non-transposed).
// ---------------------------------------------------------------------------
__global__ __launch_bounds__(320) void ffn2_ln_kernel(
    const float* __restrict__ f1, const float* __restrict__ h1,
    const float* __restrict__ W2, const float* __restrict__ b2,
    const float* __restrict__ g, const float* __restrict__ bb,
    float* __restrict__ out)
{
    constexpr int R = 8;
    __shared__ float fs[R][DFF_];
    __shared__ float hs[R][D_];
    __shared__ float ys[R][D_];
    const int base = blockIdx.x * R;
    const int tid = threadIdx.x;

    const float4* fsrc = (const float4*)(f1 + (size_t)base * DFF_);
    float4* fdst = (float4*)&fs[0][0];
    for (int i = tid; i < R * DFF_ / 4; i += 320) fdst[i] = fsrc[i];
    const float4* hsrc = (const float4*)(h1 + (size_t)base * D_);
    float4* hdst = (float4*)&hs[0][0];
    for (int i = tid; i < R * D_ / 4; i += 320) hdst[i] = hsrc[i];
    __syncthreads();

    if (tid < D_) {
        const float4* w4 = (const float4*)(W2 + (size_t)tid * DFF_);
        float acc[R];
        float bias = b2[tid];
#pragma unroll
        for (int r = 0; r < R; r++) acc[r] = bias;
        for (int d4 = 0; d4 < DFF_ / 4; d4++) {
            float4 wv = w4[d4];
#pragma unroll
            for (int r = 0; r < R; r++) {
                float4 fv = *(const float4*)&fs[r][d4 * 4];
                acc[r] += dot4(fv, wv);
            }
        }
#pragma unroll
        for (int r = 0; r < R; r++) ys[r][tid] = gelu_exact(acc[r]) + hs[r][tid];
    }
    __syncthreads();

    const int w = tid >> 6;
    const int lane = tid & 63;
    for (int r = w; r < R; r += 5) {
        float s = 0.f, ss = 0.f;
#pragma unroll
        for (int i = 0; i < 5; i++) {
            int j = lane + i * 64;
            if (j < D_) { float y = ys[r][j]; s += y; ss += y * y; }
        }
#pragma unroll
        for (int off = 32; off; off >>= 1) {
            s += __shfl_xor(s, off);
            ss += __shfl_xor(ss, off);
        }
        float mu = s * (1.0f / D_);
        float var = ss * (1.0f / D_) - mu * mu;
        float rstd = rsqrtf(var + EPS_);
        int row = base + r;
#pragma unroll
        for (int i = 0; i < 5; i++) {
            int j = lane + i * 64;
            if (j < D_) out[(size_t)row * D_ + j] = (ys[r][j] - mu) * rstd * g[j] + bb[j];
        }
    }
}

// ---------------------------------------------------------------------------
extern "C" void kernel_launch(void* const* d_in, const int* in_sizes, int n_in,
                              void* d_out, int out_size, void* d_ws, size_t ws_size,
                              hipStream_t stream)
{
    const float* x         = (const float*)d_in[0];
    const int*   index_key = (const int*)  d_in[1];
    const float* Wq = (const float*)d_in[2];
    const float* bq = (const float*)d_in[3];
    const float* Wk = (const float*)d_in[4];
    const float* bk = (const float*)d_in[5];
    const float* Wv = (const float*)d_in[6];
    const float* bv = (const float*)d_in[7];
    const float* W1 = (const float*)d_in[8];
    const float* b1 = (const float*)d_in[9];
    const float* W2 = (const float*)d_in[10];
    const float* b2 = (const float*)d_in[11];
    const float* ln1_g = (const float*)d_in[12];
    const float* ln1_b = (const float*)d_in[13];
    const float* ln2_g = (const float*)d_in[14];
    const float* ln2_b = (const float*)d_in[15];
    float* out = (float*)d_out;

    // workspace carve (floats)
    float* Q        = (float*)d_ws;                      // 576000
    float* K        = Q + 576000;
    float* V        = K + 576000;
    float* Vmean    = V + 576000;                        // 576
    float* measure  = Vmean + 576;                       // 16000
    float* wtbuf    = measure + 16000;                   // 576000 (W1T/W2T live here)
    float* h1       = wtbuf + 576000;                    // 576000
    int*   qlist    = (int*)(h1 + 576000);               // 4000 ints
    int*   slot_map = qlist + 4000;                      // 16000 ints
    float* part     = (float*)(slot_map + 16000);        // 4,000,000
    float* f1       = part;                              // dead after combine_ln1
    float* KT       = part + 4000000;                    // 576,000

    // transposed QKV weights alias the part region (dead until attn_part):
    float* WqT = part;
    float* WkT = WqT + 82944;
    float* WvT = WkT + 82944;
    // FFN transposed weights live in wtbuf (written at stream start, read last):
    float* W1T = wtbuf;                                  // 165888 floats
    float* W2T = wtbuf + 165888;                         // 165888 floats

    const size_t kt_end = 2916576ull + 4000000ull + 576000ull;  // ~30 MB
    const bool   big    = ws_size >= kt_end * sizeof(float);
    const int    nchunk = big ? 25 : 8;
    const int    chunk_len = L_ / nchunk;

    if (big) {
        weights_prep_kernel<<<567, 256, 0, stream>>>(Wq, Wk, Wv, WqT, WkT, WvT,
                                                     W1, W2, W1T, W2T);
        qkvT4_kernel<<<250, 512, 0, stream>>>(x, WqT, WkT, WvT, bq, bk, bv,
                                              Q, K, V, KT);
        score_measure4_kernel<<<BH_ * 125, 128, 0, stream>>>(Q, KT, index_key, measure);
    } else {
        qkv_kernel<<<250, 320, 0, stream>>>(x, Wq, bq, Wk, bk, Wv, bv, Q, K, V);
        measure_kernel<<<4000, 256, 0, stream>>>(Q, K, index_key, measure);
    }
    topk_vmean_kernel<<<BH_ * 4 + BH_, 256, 0, stream>>>(measure, qlist, slot_map, V, Vmean);
    attn_part3_kernel<<<BH_ * nchunk, 128, 0, stream>>>(Q, K, V, qlist, part, nchunk, chunk_len);
    combine_ln1_kernel<<<B_ * L_, 320, 0, stream>>>(x, part, slot_map, Vmean,
                                                    ln1_g, ln1_b, h1, nchunk);
    if (big) {
        ffn_gemm1_kernel<<<567, 256, 0, stream>>>(h1, W1T, b1, f1);
        ffn_gemm2_kernel<<<250, 576, 0, stream>>>(f1, h1, W2T, b2,
                                                  ln2_g, ln2_b, out);
    } else {
        ffn1_kernel<<<250, 192, 0, stream>>>(h1, W1, b1, f1);
        ffn2_ln_kernel<<<250, 320, 0, stream>>>(f1, h1, W2, b2, ln2_g, ln2_b, out);
    }
}

// Round 7
// 260.778 us; speedup vs baseline: 1.1549x; 1.1390x over previous
//
#include <hip/hip_runtime.h>
#include <math.h>

// Problem constants
#define B_ 2
#define L_ 1000
#define D_ 288
#define H_ 8
#define DIM_ 36
#define DFF_ 576
#define KS_ 250
#define NQ_ 250
#define BH_ (B_ * H_)
#define EPS_ 1e-5f
#define PSTRIDE_ 40             // partial row: 36 acc + 1 sum, padded to 40
#define MAXCL_ 125              // max chunk_len (small-ws fallback)

__device__ __forceinline__ float gelu_exact(float x) {
    return 0.5f * x * (1.0f + erff(x * 0.70710678118654752f));
}

__device__ __forceinline__ float dot4(float4 a, float4 b) {
    return a.x * b.x + a.y * b.y + a.z * b.z + a.w * b.w;
}

// ---------------------------------------------------------------------------
// K0: merged weight prep: QKV transpose (blocks 0..242) + FFN transpose
// (blocks 243..566). One launch at stream start.
// ---------------------------------------------------------------------------
__global__ __launch_bounds__(256) void weights_prep_kernel(
    const float* __restrict__ Wq, const float* __restrict__ Wk,
    const float* __restrict__ Wv,
    float* __restrict__ WqT, float* __restrict__ WkT, float* __restrict__ WvT,
    const float* __restrict__ W1, const float* __restrict__ W2,
    float* __restrict__ W1T, float* __restrict__ W2T)
{
    __shared__ float tile[32][33];
    const int tx = threadIdx.x & 31, ty = threadIdx.x >> 5;
    if (blockIdx.x < 243) {
        const int m = blockIdx.x / 81;
        const int t = blockIdx.x % 81;
        const float* src = (m == 0) ? Wq : (m == 1) ? Wk : Wv;
        float* dst = (m == 0) ? WqT : (m == 1) ? WkT : WvT;
        const int ty0 = (t / 9) * 32, tx0 = (t % 9) * 32;
#pragma unroll
        for (int i = 0; i < 4; i++)
            tile[ty + 8 * i][tx] = src[(size_t)(ty0 + ty + 8 * i) * D_ + tx0 + tx];
        __syncthreads();
#pragma unroll
        for (int i = 0; i < 4; i++)
            dst[(size_t)(tx0 + ty + 8 * i) * D_ + ty0 + tx] = tile[tx][ty + 8 * i];
    } else {
        int t = blockIdx.x - 243;
        const float* src; float* dst; int Rr, Cc, ntx;
        if (t < 162) { src = W1; dst = W1T; Rr = DFF_; Cc = D_; ntx = 9; }
        else { t -= 162; src = W2; dst = W2T; Rr = D_; Cc = DFF_; ntx = 18; }
        const int ty0 = (t / ntx) * 32, tx0 = (t % ntx) * 32;
#pragma unroll
        for (int i = 0; i < 4; i++)
            tile[ty + 8 * i][tx] = src[(size_t)(ty0 + ty + 8 * i) * Cc + tx0 + tx];
        __syncthreads();
#pragma unroll
        for (int i = 0; i < 4; i++)
            dst[(size_t)(tx0 + ty + 8 * i) * Rr + ty0 + tx] = tile[tx][ty + 8 * i];
    }
}

// ---------------------------------------------------------------------------
// K1 v3: QKV with 2-way k-split: 432 active threads (216 col-groups x 2
// k-groups of 144), block 448, grid 500 (~2 blocks/CU, 14 waves/CU).
// Emits KT directly. [Best measured config — R=8 variants regressed:
// grid 250 = 1 block/CU = latency-bound, compiler won't pipeline.]
// ---------------------------------------------------------------------------
__global__ __launch_bounds__(448) void qkvT3_kernel(
    const float* __restrict__ x,
    const float* __restrict__ WqT, const float* __restrict__ WkT,
    const float* __restrict__ WvT,
    const float* __restrict__ bq, const float* __restrict__ bk,
    const float* __restrict__ bv,
    float* __restrict__ Q, float* __restrict__ K, float* __restrict__ V,
    float* __restrict__ KT)
{
    __shared__ float xsT[D_][4];        // [k][r]  4608 B
    __shared__ float red[3456];         // kg1 partials  13824 B
    const int base = blockIdx.x * 4;
    const int tid = threadIdx.x;

    for (int idx = tid; idx < 4 * D_; idx += 448) {
        int r = idx / D_, k = idx % D_;
        xsT[k][r] = x[(size_t)(base + r) * D_ + k];
    }
    __syncthreads();

    const int kg = tid / 216;           // 0 or 1 (tid < 432)
    const int ct = tid - kg * 216;      // 0..215
    const bool active = tid < 432;

    float a[4][4];
    int m = 0, c = 0;
    if (active) {
        const int gcol = 4 * ct;              // 0..863
        m = gcol / D_;
        c = gcol - m * D_;
        const float* WT = (m == 0) ? WqT : (m == 1) ? WkT : WvT;
        const float* bias = (m == 0) ? bq : (m == 1) ? bk : bv;
#pragma unroll
        for (int j = 0; j < 4; j++) {
            float bv2 = (kg == 0) ? bias[c + j] : 0.f;
#pragma unroll
            for (int r = 0; r < 4; r++) a[j][r] = bv2;
        }
        const int kbeg = kg * 144;
        for (int k = kbeg; k < kbeg + 144; k++) {
            float4 w = *(const float4*)(WT + (size_t)k * D_ + c);
            float4 xv = *(const float4*)&xsT[k][0];
            a[0][0] += w.x * xv.x; a[0][1] += w.x * xv.y; a[0][2] += w.x * xv.z; a[0][3] += w.x * xv.w;
            a[1][0] += w.y * xv.x; a[1][1] += w.y * xv.y; a[1][2] += w.y * xv.z; a[1][3] += w.y * xv.w;
            a[2][0] += w.z * xv.x; a[2][1] += w.z * xv.y; a[2][2] += w.z * xv.z; a[2][3] += w.z * xv.w;
            a[3][0] += w.w * xv.x; a[3][1] += w.w * xv.y; a[3][2] += w.w * xv.z; a[3][3] += w.w * xv.w;
        }
        if (kg == 1) {
#pragma unroll
            for (int j = 0; j < 4; j++)
                *(float4*)&red[(j * 216 + ct) * 4] =
                    make_float4(a[j][0], a[j][1], a[j][2], a[j][3]);
        }
    }
    __syncthreads();

    if (active && kg == 0) {
        const int bb_ = base / L_;             // block never spans b boundary
        const int l0 = base % L_;
        float* outp = (m == 0) ? Q : (m == 1) ? K : V;
#pragma unroll
        for (int j = 0; j < 4; j++) {
            float4 o = *(const float4*)&red[(j * 216 + ct) * 4];
            a[j][0] += o.x; a[j][1] += o.y; a[j][2] += o.z; a[j][3] += o.w;
            int col = c + j;
            int h = col / DIM_, dd = col % DIM_;
#pragma unroll
            for (int r = 0; r < 4; r++) {
                int row = base + r;
                int b = row / L_, l = row % L_;
                outp[((size_t)(b * H_ + h) * L_ + l) * DIM_ + dd] = a[j][r];
            }
            if (m == 1) {
                *(float4*)(KT + ((size_t)(bb_ * H_ + h) * DIM_ + dd) * L_ + l0) =
                    make_float4(a[j][0], a[j][1], a[j][2], a[j][3]);
            }
        }
    }
}

// ---------------------------------------------------------------------------
// K1-fallback: qkv with row-major weights (small-ws path, no KT).
// ---------------------------------------------------------------------------
__global__ __launch_bounds__(320) void qkv_kernel(
    const float* __restrict__ x,
    const float* __restrict__ Wq, const float* __restrict__ bq,
    const float* __restrict__ Wk, const float* __restrict__ bk,
    const float* __restrict__ Wv, const float* __restrict__ bv,
    float* __restrict__ Q, float* __restrict__ K, float* __restrict__ V)
{
    constexpr int R = 8;
    __shared__ float xs[R][D_];
    const int base = blockIdx.x * R;
    const int tid = threadIdx.x;

    const float4* xsrc = (const float4*)(x + (size_t)base * D_);
    float4* xdst = (float4*)&xs[0][0];
    for (int i = tid; i < R * D_ / 4; i += 320) xdst[i] = xsrc[i];
    __syncthreads();

    if (tid < D_) {
        const float4* wq4 = (const float4*)(Wq + (size_t)tid * D_);
        const float4* wk4 = (const float4*)(Wk + (size_t)tid * D_);
        const float4* wv4 = (const float4*)(Wv + (size_t)tid * D_);
        float aq[R], ak[R], av[R];
        float biasq = bq[tid], biask = bk[tid], biasv = bv[tid];
#pragma unroll
        for (int r = 0; r < R; r++) { aq[r] = biasq; ak[r] = biask; av[r] = biasv; }
        for (int d4 = 0; d4 < D_ / 4; d4++) {
            float4 wqv = wq4[d4], wkv = wk4[d4], wvv = wv4[d4];
#pragma unroll
            for (int r = 0; r < R; r++) {
                float4 hv = *(const float4*)&xs[r][d4 * 4];
                aq[r] += dot4(hv, wqv);
                ak[r] += dot4(hv, wkv);
                av[r] += dot4(hv, wvv);
            }
        }
        const int h = tid / DIM_, dd = tid % DIM_;
#pragma unroll
        for (int r = 0; r < R; r++) {
            int row = base + r;
            int b = row / L_, l = row % L_;
            size_t o = ((size_t)(b * H_ + h) * L_ + l) * DIM_ + dd;
            Q[o] = aq[r]; K[o] = ak[r]; V[o] = av[r];
        }
    }
}

// ---------------------------------------------------------------------------
// K3: FUSED score+measure. grid 2000, block 256.
// ---------------------------------------------------------------------------
__global__ __launch_bounds__(256) void score_measure3_kernel(
    const float* __restrict__ Q, const float* __restrict__ KT,
    const int* __restrict__ index_key, float* __restrict__ measure)
{
    constexpr int R = 8;
    __shared__ float qs[R][DIM_];
    __shared__ float st[R][1004];
    const int bh = blockIdx.x / 125;
    const int qt = blockIdx.x % 125;
    const int tid = threadIdx.x;

    if (tid < R * DIM_ / 4)
        ((float4*)&qs[0][0])[tid] =
            ((const float4*)(Q + ((size_t)bh * L_ + qt * R) * DIM_))[tid];
    __syncthreads();

    const float* KTb = KT + (size_t)bh * DIM_ * L_;
#pragma unroll
    for (int i = 0; i < 4; i++) {
        const int k = i * 256 + tid;
        if (k < L_) {
            float acc[R];
#pragma unroll
            for (int r = 0; r < R; r++) acc[r] = 0.f;
#pragma unroll
            for (int d4 = 0; d4 < DIM_ / 4; d4++) {
                float4 kv;
                kv.x = KTb[(size_t)(d4 * 4 + 0) * L_ + k];
                kv.y = KTb[(size_t)(d4 * 4 + 1) * L_ + k];
                kv.z = KTb[(size_t)(d4 * 4 + 2) * L_ + k];
                kv.w = KTb[(size_t)(d4 * 4 + 3) * L_ + k];
#pragma unroll
                for (int r = 0; r < R; r++)
                    acc[r] += dot4(*(const float4*)&qs[r][d4 * 4], kv);
            }
#pragma unroll
            for (int r = 0; r < R; r++) st[r][k] = acc[r];
        }
    }
    __syncthreads();

    const int r = tid >> 5;             // 0..7
    const int lane = tid & 31;
    const int l = qt * R + r;
    const int* ik = index_key + l * KS_;
    float mx = -1e30f, sm = 0.f;
    for (int s = lane; s < KS_; s += 32) {
        float v = st[r][ik[s]];
        mx = fmaxf(mx, v);
        sm += v;
    }
#pragma unroll
    for (int off = 16; off; off >>= 1) {
        mx = fmaxf(mx, __shfl_xor(mx, off));
        sm += __shfl_xor(sm, off);
    }
    if (lane == 0) measure[bh * L_ + l] = mx - sm * (1.0f / (float)L_);
}

// ---------------------------------------------------------------------------
// K3-fallback: gather-based measure.
// ---------------------------------------------------------------------------
__global__ __launch_bounds__(256) void measure_kernel(
    const float* __restrict__ Q, const float* __restrict__ K,
    const int* __restrict__ index_key, float* __restrict__ measure)
{
    const int w = threadIdx.x >> 6;
    const int lane = threadIdx.x & 63;
    const int wid = blockIdx.x * 4 + w;
    const int bh = wid / L_;
    const int l = wid % L_;

    const float4* qp = (const float4*)(Q + ((size_t)bh * L_ + l) * DIM_);
    float4 q[9];
#pragma unroll
    for (int i = 0; i < 9; i++) q[i] = qp[i];

    const int* ik = index_key + l * KS_;
    const float* Kb = K + (size_t)bh * L_ * DIM_;

    float mx = -1e30f, sm = 0.f;
#pragma unroll
    for (int s = lane; s < KS_; s += 64) {
        int kidx = ik[s];
        const float4* k4 = (const float4*)(Kb + (size_t)kidx * DIM_);
        float acc = 0.f;
#pragma unroll
        for (int i = 0; i < 9; i++) acc += dot4(q[i], k4[i]);
        mx = fmaxf(mx, acc);
        sm += acc;
    }
#pragma unroll
    for (int off = 32; off; off >>= 1) {
        mx = fmaxf(mx, __shfl_xor(mx, off));
        sm += __shfl_xor(sm, off);
    }
    if (lane == 0) measure[wid] = mx - sm * (1.0f / (float)L_);
}

// ---------------------------------------------------------------------------
// K4+K2 merged: top-NQ rank-based (blocks 0..63) + Vmean (blocks 64..79).
// ---------------------------------------------------------------------------
__global__ __launch_bounds__(256) void topk_vmean_kernel(
    const float* __restrict__ measure, int* __restrict__ qlist,
    int* __restrict__ slot_map, const float* __restrict__ V,
    float* __restrict__ Vmean)
{
    if (blockIdx.x < BH_ * 4) {
        const int bh = blockIdx.x >> 2;
        const int quarter = blockIdx.x & 3;
        __shared__ float m[L_];
        for (int i = threadIdx.x; i < L_; i += 256) m[i] = measure[bh * L_ + i];
        __syncthreads();
        const int i = quarter * 250 + threadIdx.x;
        if (threadIdx.x < 250) {
            float mi = m[i];
            int rank = 0;
            for (int j = 0; j < L_; j++) {
                float mj = m[j];
                rank += (mj > mi) || (mj == mi && j < i);
            }
            if (rank < NQ_) qlist[bh * NQ_ + rank] = i;
            slot_map[bh * L_ + i] = (rank < NQ_) ? rank : -1;
        }
    } else {
        const int bh = blockIdx.x - BH_ * 4;
        const int tid = threadIdx.x;
        __shared__ float red2[7][DIM_];
        if (tid < 252) {
            int gq = tid / DIM_, d = tid % DIM_;
            const float* basep = V + (size_t)bh * L_ * DIM_;
            float s = 0.f;
            for (int l = gq; l < L_; l += 7) s += basep[l * DIM_ + d];
            red2[gq][d] = s;
        }
        __syncthreads();
        if (tid < DIM_) {
            float s = 0.f;
#pragma unroll
            for (int gq = 0; gq < 7; gq++) s += red2[gq][tid];
            Vmean[bh * DIM_ + tid] = s * (1.0f / L_);
        }
    }
}

// ---------------------------------------------------------------------------
// K6 v2: attention partials, K/V chunk staged in LDS. grid BH_*nchunk.
// ---------------------------------------------------------------------------
__global__ __launch_bounds__(256) void attn_part2_kernel(
    const float* __restrict__ Q, const float* __restrict__ K,
    const float* __restrict__ V, const int* __restrict__ qlist,
    float* __restrict__ part, int nchunk, int chunk_len)
{
    __shared__ float Ks[MAXCL_ * DIM_];
    __shared__ float Vs[MAXCL_ * DIM_];
    const int bh = blockIdx.x / nchunk;
    const int chunk = blockIdx.x % nchunk;
    const int tid = threadIdx.x;
    const int k0 = chunk * chunk_len;

    {
        const float4* Ksrc = (const float4*)(K + ((size_t)bh * L_ + k0) * DIM_);
        const float4* Vsrc = (const float4*)(V + ((size_t)bh * L_ + k0) * DIM_);
        const int nf4 = chunk_len * (DIM_ / 4);
        for (int i = tid; i < nf4; i += 256) {
            ((float4*)Ks)[i] = Ksrc[i];
            ((float4*)Vs)[i] = Vsrc[i];
        }
    }
    __syncthreads();

    const int slot = tid;
    if (slot >= NQ_) return;

    const int qidx = qlist[bh * NQ_ + slot];
    const float4* qp = (const float4*)(Q + ((size_t)bh * L_ + qidx) * DIM_);
    float4 q[9];
#pragma unroll
    for (int i = 0; i < 9; i++) q[i] = qp[i];

    const float scale = (float)(1.0 / 6.0);
    float4 acc[9];
#pragma unroll
    for (int i = 0; i < 9; i++) acc[i] = make_float4(0.f, 0.f, 0.f, 0.f);
    float sum = 0.f;

    for (int j = 0; j < chunk_len; j++) {
        const float4* kp = (const float4*)(Ks + j * DIM_);   // broadcast
        float s = 0.f;
#pragma unroll
        for (int i = 0; i < 9; i++) s += dot4(q[i], kp[i]);
        float e = __expf(s * scale);
        sum += e;
        const float4* vp = (const float4*)(Vs + j * DIM_);   // broadcast
#pragma unroll
        for (int i = 0; i < 9; i++) {
            float4 vv = vp[i];
            acc[i].x += e * vv.x;
            acc[i].y += e * vv.y;
            acc[i].z += e * vv.z;
            acc[i].w += e * vv.w;
        }
    }

    float* p = part + ((size_t)(bh * NQ_ + slot) * nchunk + chunk) * PSTRIDE_;
#pragma unroll
    for (int i = 0; i < 9; i++) ((float4*)p)[i] = acc[i];
    p[DIM_] = sum;
}

// ---------------------------------------------------------------------------
// K7+K8 fused: combine partials (or Vmean) + residual + LN1. grid 2000.
// ---------------------------------------------------------------------------
__global__ __launch_bounds__(320) void combine_ln1_kernel(
    const float* __restrict__ x, const float* __restrict__ part,
    const int* __restrict__ slot_map, const float* __restrict__ Vmean,
    const float* __restrict__ g, const float* __restrict__ bb,
    float* __restrict__ h1, int nchunk)
{
    const int row = blockIdx.x;          // 0..B_*L_-1
    const int b = row / L_, l = row % L_;
    const int tid = threadIdx.x;
    __shared__ float psum[5], pssq[5];

    float y = 0.f;
    if (tid < D_) {
        const int h = tid / DIM_, d = tid % DIM_;
        const int bh = b * H_ + h;
        const int slot = slot_map[bh * L_ + l];
        float v;
        if (slot < 0) {
            v = Vmean[bh * DIM_ + d];
        } else {
            const float* p = part + (size_t)(bh * NQ_ + slot) * nchunk * PSTRIDE_;
            float a = 0.f, s = 0.f;
            for (int c = 0; c < nchunk; c++) {
                a += p[c * PSTRIDE_ + d];
                s += p[c * PSTRIDE_ + DIM_];
            }
            v = a / s;
        }
        y = x[(size_t)row * D_ + tid] + v;
    }

    float s1 = y, s2 = y * y;
#pragma unroll
    for (int off = 32; off; off >>= 1) {
        s1 += __shfl_xor(s1, off);
        s2 += __shfl_xor(s2, off);
    }
    const int w = tid >> 6, lane = tid & 63;
    if (lane == 0) { psum[w] = s1; pssq[w] = s2; }
    __syncthreads();
    float ts = 0.f, tq = 0.f;
#pragma unroll
    for (int i = 0; i < 5; i++) { ts += psum[i]; tq += pssq[i]; }
    float mu = ts * (1.0f / D_);
    float var = tq * (1.0f / D_) - mu * mu;
    float rstd = rsqrtf(var + EPS_);
    if (tid < D_)
        h1[(size_t)row * D_ + tid] = (y - mu) * rstd * g[tid] + bb[tid];
}

// ---------------------------------------------------------------------------
// K9 v4: fused FFN, R=4, block 576 (deep k-split -> 18 waves/CU).
// Phase1: 144 ct x 4 kg (72 k each). Phase2: 72 ct x 8 kg (72 k each).
// Transposed activation LDS (one b128 broadcast per k). grid 500.
// [Best measured FFN: fused beats split gemm1+gemm2 by ~20us total —
// the f1 round-trip + extra launch outweigh the k-split barriers.]
// ---------------------------------------------------------------------------
__global__ __launch_bounds__(576) void ffn_fused4_kernel(
    const float* __restrict__ h1,
    const float* __restrict__ W1T, const float* __restrict__ b1,
    const float* __restrict__ W2T, const float* __restrict__ b2,
    const float* __restrict__ g, const float* __restrict__ bb,
    float* __restrict__ out)
{
    constexpr int R = 4;
    __shared__ float hsT[D_][R];      // 4608 B  [k][r]
    __shared__ float fsT[DFF_][R];    // 9216 B  [k][r]
    __shared__ float red[8064];       // 32256 B (max of 3*576*4, 7*288*4)
    __shared__ float ys[R][D_];       // 4608 B
    const int base = blockIdx.x * R;
    const int tid = threadIdx.x;

    for (int idx = tid; idx < R * D_; idx += 576) {
        int r = idx / D_, k = idx % D_;
        hsT[k][r] = h1[(size_t)(base + r) * D_ + k];
    }
    __syncthreads();

    // phase 1: f = gelu(h1 @ W1T + b1); 144 col-groups x 4 k-groups of 72
    {
        const int kg = tid / 144;          // 0..3
        const int ct = tid - kg * 144;     // 0..143
        const int c = 4 * ct;
        float a[4][4];
#pragma unroll
        for (int j = 0; j < 4; j++) {
            float bv = (kg == 0) ? b1[c + j] : 0.f;
#pragma unroll
            for (int r = 0; r < 4; r++) a[j][r] = bv;
        }
        const int kbeg = kg * 72;
        for (int k = kbeg; k < kbeg + 72; k++) {
            float4 w = *(const float4*)(W1T + (size_t)k * DFF_ + c);
            float4 xv = *(const float4*)&hsT[k][0];
            a[0][0] += w.x * xv.x; a[0][1] += w.x * xv.y; a[0][2] += w.x * xv.z; a[0][3] += w.x * xv.w;
            a[1][0] += w.y * xv.x; a[1][1] += w.y * xv.y; a[1][2] += w.y * xv.z; a[1][3] += w.y * xv.w;
            a[2][0] += w.z * xv.x; a[2][1] += w.z * xv.y; a[2][2] += w.z * xv.z; a[2][3] += w.z * xv.w;
            a[3][0] += w.w * xv.x; a[3][1] += w.w * xv.y; a[3][2] += w.w * xv.z; a[3][3] += w.w * xv.w;
        }
        if (kg >= 1) {
#pragma unroll
            for (int j = 0; j < 4; j++)
                *(float4*)&red[(((kg - 1) * 576) + j * 144 + ct) * 4] =
                    make_float4(a[j][0], a[j][1], a[j][2], a[j][3]);
        }
        __syncthreads();
        if (kg == 0) {
#pragma unroll
            for (int j = 0; j < 4; j++) {
                float4 o0 = *(const float4*)&red[((0 * 576) + j * 144 + ct) * 4];
                float4 o1 = *(const float4*)&red[((1 * 576) + j * 144 + ct) * 4];
                float4 o2 = *(const float4*)&red[((2 * 576) + j * 144 + ct) * 4];
                float y0 = gelu_exact(a[j][0] + o0.x + o1.x + o2.x);
                float y1 = gelu_exact(a[j][1] + o0.y + o1.y + o2.y);
                float y2 = gelu_exact(a[j][2] + o0.z + o1.z + o2.z);
                float y3 = gelu_exact(a[j][3] + o0.w + o1.w + o2.w);
                *(float4*)&fsT[c + j][0] = make_float4(y0, y1, y2, y3);
            }
        }
    }
    __syncthreads();

    // phase 2: y = gelu(f @ W2T + b2) + h1; 72 col-groups x 8 k-groups of 72
    {
        const int kg = tid / 72;           // 0..7
        const int ct = tid - kg * 72;      // 0..71
        const int c = 4 * ct;
        float a[4][4];
#pragma unroll
        for (int j = 0; j < 4; j++) {
            float bv = (kg == 0) ? b2[c + j] : 0.f;
#pragma unroll
            for (int r = 0; r < 4; r++) a[j][r] = bv;
        }
        const int kbeg = kg * 72;
        for (int k = kbeg; k < kbeg + 72; k++) {
            float4 w = *(const float4*)(W2T + (size_t)k * D_ + c);
            float4 fv = *(const float4*)&fsT[k][0];
            a[0][0] += w.x * fv.x; a[0][1] += w.x * fv.y; a[0][2] += w.x * fv.z; a[0][3] += w.x * fv.w;
            a[1][0] += w.y * fv.x; a[1][1] += w.y * fv.y; a[1][2] += w.y * fv.z; a[1][3] += w.y * fv.w;
            a[2][0] += w.z * fv.x; a[2][1] += w.z * fv.y; a[2][2] += w.z * fv.z; a[2][3] += w.z * fv.w;
            a[3][0] += w.w * fv.x; a[3][1] += w.w * fv.y; a[3][2] += w.w * fv.z; a[3][3] += w.w * fv.w;
        }
        if (kg >= 1) {
#pragma unroll
            for (int j = 0; j < 4; j++)
                *(float4*)&red[(((kg - 1) * 288) + j * 72 + ct) * 4] =
                    make_float4(a[j][0], a[j][1], a[j][2], a[j][3]);
        }
        __syncthreads();
        if (kg == 0) {
            float y[4][4];
#pragma unroll
            for (int j = 0; j < 4; j++) {
                float t0 = a[j][0], t1 = a[j][1], t2 = a[j][2], t3 = a[j][3];
#pragma unroll
                for (int kk = 0; kk < 7; kk++) {
                    float4 o = *(const float4*)&red[((kk * 288) + j * 72 + ct) * 4];
                    t0 += o.x; t1 += o.y; t2 += o.z; t3 += o.w;
                }
                float4 hres = *(const float4*)&hsT[c + j][0];
                y[j][0] = gelu_exact(t0) + hres.x;
                y[j][1] = gelu_exact(t1) + hres.y;
                y[j][2] = gelu_exact(t2) + hres.z;
                y[j][3] = gelu_exact(t3) + hres.w;
            }
#pragma unroll
            for (int r = 0; r < 4; r++)
                *(float4*)&ys[r][c] = make_float4(y[0][r], y[1][r], y[2][r], y[3][r]);
        }
    }
    __syncthreads();

    // phase 3: LN2, waves 0..3, one row each
    const int w = tid >> 6;
    const int lane = tid & 63;
    if (w < 4) {
        const int r = w;
        float s = 0.f, ss = 0.f;
#pragma unroll
        for (int i = 0; i < 5; i++) {
            int j = lane + i * 64;
            if (j < D_) { float yv = ys[r][j]; s += yv; ss += yv * yv; }
        }
#pragma unroll
        for (int off = 32; off; off >>= 1) {
            s += __shfl_xor(s, off);
            ss += __shfl_xor(ss, off);
        }
        float mu = s * (1.0f / D_);
        float var = ss * (1.0f / D_) - mu * mu;
        float rstd = rsqrtf(var + EPS_);
        int row = base + r;
#pragma unroll
        for (int i = 0; i < 5; i++) {
            int j = lane + i * 64;
            if (j < D_)
                out[(size_t)row * D_ + j] = (ys[r][j] - mu) * rstd * g[j] + bb[j];
        }
    }
}

// ---------------------------------------------------------------------------
// K9-fallback: FFN layer 1, 3 cols/thread. grid 250, block 192.
// ---------------------------------------------------------------------------
__global__ __launch_bounds__(192) void ffn1_kernel(
    const float* __restrict__ h1,
    const float* __restrict__ W1, const float* __restrict__ b1,
    float* __restrict__ f1)
{
    constexpr int R = 8;
    __shared__ float hs[R][D_];
    const int base = blockIdx.x * R;
    const int tid = threadIdx.x;

    const float4* hsrc = (const float4*)(h1 + (size_t)base * D_);
    float4* hdst = (float4*)&hs[0][0];
    for (int i = tid; i < R * D_ / 4; i += 192) hdst[i] = hsrc[i];
    __syncthreads();

    const int j0 = tid, j1 = tid + 192, j2 = tid + 384;
    const float4* w0 = (const float4*)(W1 + (size_t)j0 * D_);
    const float4* w1 = (const float4*)(W1 + (size_t)j1 * D_);
    const float4* w2 = (const float4*)(W1 + (size_t)j2 * D_);
    float a0[R], a1[R], a2[R];
    float bb0 = b1[j0], bb1 = b1[j1], bb2 = b1[j2];
#pragma unroll
    for (int r = 0; r < R; r++) { a0[r] = bb0; a1[r] = bb1; a2[r] = bb2; }

    for (int d4 = 0; d4 < D_ / 4; d4++) {
        float4 x0 = w0[d4], x1 = w1[d4], x2 = w2[d4];
#pragma unroll
        for (int r = 0; r < R; r++) {
            float4 hv = *(const float4*)&hs[r][d4 * 4];
            a0[r] += dot4(hv, x0);
            a1[r] += dot4(hv, x1);
            a2[r] += dot4(hv, x2);
        }
    }
#pragma unroll
    for (int r = 0; r < R; r++) {
        size_t rowo = (size_t)(base + r) * DFF_;
        f1[rowo + j0] = gelu_exact(a0[r]);
        f1[rowo + j1] = gelu_exact(a1[r]);
        f1[rowo + j2] = gelu_exact(a2[r]);
    }
}

// ---------------------------------------------------------------------------
// K10-fallback: FFN layer 2 + residual + LN2 (non-transposed).
// ---------------------------------------------------------------------------
__global__ __launch_bounds__(320) void ffn2_ln_kernel(
    const float* __restrict__ f1, const float* __restrict__ h1,
    const float* __restrict__ W2, const float* __restrict__ b2,
    const float* __restrict__ g, const float* __restrict__ bb,
    float* __restrict__ out)
{
    constexpr int R = 8;
    __shared__ float fs[R][DFF_];
    __shared__ float hs[R][D_];
    __shared__ float ys[R][D_];
    const int base = blockIdx.x * R;
    const int tid = threadIdx.x;

    const float4* fsrc = (const float4*)(f1 + (size_t)base * DFF_);
    float4* fdst = (float4*)&fs[0][0];
    for (int i = tid; i < R * DFF_ / 4; i += 320) fdst[i] = fsrc[i];
    const float4* hsrc = (const float4*)(h1 + (size_t)base * D_);
    float4* hdst = (float4*)&hs[0][0];
    for (int i = tid; i < R * D_ / 4; i += 320) hdst[i] = hsrc[i];
    __syncthreads();

    if (tid < D_) {
        const float4* w4 = (const float4*)(W2 + (size_t)tid * DFF_);
        float acc[R];
        float bias = b2[tid];
#pragma unroll
        for (int r = 0; r < R; r++) acc[r] = bias;
        for (int d4 = 0; d4 < DFF_ / 4; d4++) {
            float4 wv = w4[d4];
#pragma unroll
            for (int r = 0; r < R; r++) {
                float4 fv = *(const float4*)&fs[r][d4 * 4];
                acc[r] += dot4(fv, wv);
            }
        }
#pragma unroll
        for (int r = 0; r < R; r++) ys[r][tid] = gelu_exact(acc[r]) + hs[r][tid];
    }
    __syncthreads();

    const int w = tid >> 6;
    const int lane = tid & 63;
    for (int r = w; r < R; r += 5) {
        float s = 0.f, ss = 0.f;
#pragma unroll
        for (int i = 0; i < 5; i++) {
            int j = lane + i * 64;
            if (j < D_) { float y = ys[r][j]; s += y; ss += y * y; }
        }
#pragma unroll
        for (int off = 32; off; off >>= 1) {
            s += __shfl_xor(s, off);
            ss += __shfl_xor(ss, off);
        }
        float mu = s * (1.0f / D_);
        float var = ss * (1.0f / D_) - mu * mu;
        float rstd = rsqrtf(var + EPS_);
        int row = base + r;
#pragma unroll
        for (int i = 0; i < 5; i++) {
            int j = lane + i * 64;
            if (j < D_) out[(size_t)row * D_ + j] = (ys[r][j] - mu) * rstd * g[j] + bb[j];
        }
    }
}

// ---------------------------------------------------------------------------
extern "C" void kernel_launch(void* const* d_in, const int* in_sizes, int n_in,
                              void* d_out, int out_size, void* d_ws, size_t ws_size,
                              hipStream_t stream)
{
    const float* x         = (const float*)d_in[0];
    const int*   index_key = (const int*)  d_in[1];
    const float* Wq = (const float*)d_in[2];
    const float* bq = (const float*)d_in[3];
    const float* Wk = (const float*)d_in[4];
    const float* bk = (const float*)d_in[5];
    const float* Wv = (const float*)d_in[6];
    const float* bv = (const float*)d_in[7];
    const float* W1 = (const float*)d_in[8];
    const float* b1 = (const float*)d_in[9];
    const float* W2 = (const float*)d_in[10];
    const float* b2 = (const float*)d_in[11];
    const float* ln1_g = (const float*)d_in[12];
    const float* ln1_b = (const float*)d_in[13];
    const float* ln2_g = (const float*)d_in[14];
    const float* ln2_b = (const float*)d_in[15];
    float* out = (float*)d_out;

    // workspace carve (floats)
    float* Q        = (float*)d_ws;                      // 576000
    float* K        = Q + 576000;
    float* V        = K + 576000;
    float* Vmean    = V + 576000;                        // 576
    float* measure  = Vmean + 576;                       // 16000
    float* wtbuf    = measure + 16000;                   // 576000 (W1T/W2T live here)
    float* h1       = wtbuf + 576000;                    // 576000
    int*   qlist    = (int*)(h1 + 576000);               // 4000 ints
    int*   slot_map = qlist + 4000;                      // 16000 ints
    float* part     = (float*)(slot_map + 16000);        // 4,000,000
    float* f1       = part;                              // fallback only
    float* KT       = part + 4000000;                    // 576,000

    // transposed QKV weights alias the part region (dead until attn_part):
    float* WqT = part;
    float* WkT = WqT + 82944;
    float* WvT = WkT + 82944;
    // FFN transposed weights live in wtbuf (written at stream start, read last):
    float* W1T = wtbuf;                                  // 165888 floats
    float* W2T = wtbuf + 165888;                         // 165888 floats

    const size_t kt_end = 2916576ull + 4000000ull + 576000ull;  // ~30 MB
    const bool   big    = ws_size >= kt_end * sizeof(float);
    const int    nchunk = big ? 25 : 8;
    const int    chunk_len = L_ / nchunk;

    if (big) {
        weights_prep_kernel<<<567, 256, 0, stream>>>(Wq, Wk, Wv, WqT, WkT, WvT,
                                                     W1, W2, W1T, W2T);
        qkvT3_kernel<<<500, 448, 0, stream>>>(x, WqT, WkT, WvT, bq, bk, bv,
                                              Q, K, V, KT);
        score_measure3_kernel<<<BH_ * 125, 256, 0, stream>>>(Q, KT, index_key, measure);
    } else {
        qkv_kernel<<<250, 320, 0, stream>>>(x, Wq, bq, Wk, bk, Wv, bv, Q, K, V);
        measure_kernel<<<4000, 256, 0, stream>>>(Q, K, index_key, measure);
    }
    topk_vmean_kernel<<<BH_ * 4 + BH_, 256, 0, stream>>>(measure, qlist, slot_map, V, Vmean);
    attn_part2_kernel<<<BH_ * nchunk, 256, 0, stream>>>(Q, K, V, qlist, part, nchunk, chunk_len);
    combine_ln1_kernel<<<B_ * L_, 320, 0, stream>>>(x, part, slot_map, Vmean,
                                                    ln1_g, ln1_b, h1, nchunk);
    if (big) {
        ffn_fused4_kernel<<<500, 576, 0, stream>>>(h1, W1T, b1, W2T, b2,
                                                   ln2_g, ln2_b, out);
    } else {
        ffn1_kernel<<<250, 192, 0, stream>>>(h1, W1, b1, f1);
        ffn2_ln_kernel<<<250, 320, 0, stream>>>(f1, h1, W2, b2, ln2_g, ln2_b, out);
    }
}

// Round 8
// 258.233 us; speedup vs baseline: 1.1663x; 1.0099x over previous
//
#include <hip/hip_runtime.h>
#include <math.h>

// Problem constants
#define B_ 2
#define L_ 1000
#define D_ 288
#define H_ 8
#define DIM_ 36
#define DFF_ 576
#define KS_ 250
#define NQ_ 250
#define BH_ (B_ * H_)
#define EPS_ 1e-5f
#define PSTRIDE_ 40             // partial row: 36 acc + 1 sum, padded to 40
#define MAXCL_ 125              // max chunk_len (small-ws fallback)

__device__ __forceinline__ float gelu_exact(float x) {
    return 0.5f * x * (1.0f + erff(x * 0.70710678118654752f));
}

__device__ __forceinline__ float dot4(float4 a, float4 b) {
    return a.x * b.x + a.y * b.y + a.z * b.z + a.w * b.w;
}

// ---------------------------------------------------------------------------
// K0: merged weight prep: QKV transpose (blocks 0..242) + FFN transpose
// (blocks 243..566). One launch at stream start.
// ---------------------------------------------------------------------------
__global__ __launch_bounds__(256) void weights_prep_kernel(
    const float* __restrict__ Wq, const float* __restrict__ Wk,
    const float* __restrict__ Wv,
    float* __restrict__ WqT, float* __restrict__ WkT, float* __restrict__ WvT,
    const float* __restrict__ W1, const float* __restrict__ W2,
    float* __restrict__ W1T, float* __restrict__ W2T)
{
    __shared__ float tile[32][33];
    const int tx = threadIdx.x & 31, ty = threadIdx.x >> 5;
    if (blockIdx.x < 243) {
        const int m = blockIdx.x / 81;
        const int t = blockIdx.x % 81;
        const float* src = (m == 0) ? Wq : (m == 1) ? Wk : Wv;
        float* dst = (m == 0) ? WqT : (m == 1) ? WkT : WvT;
        const int ty0 = (t / 9) * 32, tx0 = (t % 9) * 32;
#pragma unroll
        for (int i = 0; i < 4; i++)
            tile[ty + 8 * i][tx] = src[(size_t)(ty0 + ty + 8 * i) * D_ + tx0 + tx];
        __syncthreads();
#pragma unroll
        for (int i = 0; i < 4; i++)
            dst[(size_t)(tx0 + ty + 8 * i) * D_ + ty0 + tx] = tile[tx][ty + 8 * i];
    } else {
        int t = blockIdx.x - 243;
        const float* src; float* dst; int Rr, Cc, ntx;
        if (t < 162) { src = W1; dst = W1T; Rr = DFF_; Cc = D_; ntx = 9; }
        else { t -= 162; src = W2; dst = W2T; Rr = D_; Cc = DFF_; ntx = 18; }
        const int ty0 = (t / ntx) * 32, tx0 = (t % ntx) * 32;
#pragma unroll
        for (int i = 0; i < 4; i++)
            tile[ty + 8 * i][tx] = src[(size_t)(ty0 + ty + 8 * i) * Cc + tx0 + tx];
        __syncthreads();
#pragma unroll
        for (int i = 0; i < 4; i++)
            dst[(size_t)(tx0 + ty + 8 * i) * Rr + ty0 + tx] = tile[tx][ty + 8 * i];
    }
}

// ---------------------------------------------------------------------------
// K1 v3p: QKV, 2-way k-split, block 448, grid 500. Emits KT directly.
// NEW: manual double-buffered weight-load batches (4 float4 ahead) — the
// compiler's minimal-VGPR allocation (32-44 regs) left 1 load in flight
// and 69-84% exposed L2 latency (R5-R7 counters).
// ---------------------------------------------------------------------------
__global__ __launch_bounds__(448) void qkvT3_kernel(
    const float* __restrict__ x,
    const float* __restrict__ WqT, const float* __restrict__ WkT,
    const float* __restrict__ WvT,
    const float* __restrict__ bq, const float* __restrict__ bk,
    const float* __restrict__ bv,
    float* __restrict__ Q, float* __restrict__ K, float* __restrict__ V,
    float* __restrict__ KT)
{
    __shared__ float xsT[D_][4];        // [k][r]  4608 B
    __shared__ float red[3456];         // kg1 partials  13824 B
    const int base = blockIdx.x * 4;
    const int tid = threadIdx.x;

    for (int idx = tid; idx < 4 * D_; idx += 448) {
        int r = idx / D_, k = idx % D_;
        xsT[k][r] = x[(size_t)(base + r) * D_ + k];
    }
    __syncthreads();

    const int kg = tid / 216;           // 0 or 1 (tid < 432)
    const int ct = tid - kg * 216;      // 0..215
    const bool active = tid < 432;

    float a[4][4];
    int m = 0, c = 0;
    if (active) {
        const int gcol = 4 * ct;              // 0..863
        m = gcol / D_;
        c = gcol - m * D_;
        const float* WT = (m == 0) ? WqT : (m == 1) ? WkT : WvT;
        const float* bias = (m == 0) ? bq : (m == 1) ? bk : bv;
#pragma unroll
        for (int j = 0; j < 4; j++) {
            float bv2 = (kg == 0) ? bias[c + j] : 0.f;
#pragma unroll
            for (int r = 0; r < 4; r++) a[j][r] = bv2;
        }

        auto fma16 = [&a](const float4 w, const float4 xv) {
            a[0][0] += w.x * xv.x; a[0][1] += w.x * xv.y; a[0][2] += w.x * xv.z; a[0][3] += w.x * xv.w;
            a[1][0] += w.y * xv.x; a[1][1] += w.y * xv.y; a[1][2] += w.y * xv.z; a[1][3] += w.y * xv.w;
            a[2][0] += w.z * xv.x; a[2][1] += w.z * xv.y; a[2][2] += w.z * xv.z; a[2][3] += w.z * xv.w;
            a[3][0] += w.w * xv.x; a[3][1] += w.w * xv.y; a[3][2] += w.w * xv.z; a[3][3] += w.w * xv.w;
        };

        const int kbeg = kg * 144;
        const float* wbase = WT + (size_t)kbeg * D_ + c;
        float4 wb0 = *(const float4*)(wbase + 0 * D_);
        float4 wb1 = *(const float4*)(wbase + 1 * D_);
        float4 wb2 = *(const float4*)(wbase + 2 * D_);
        float4 wb3 = *(const float4*)(wbase + 3 * D_);
        int kk = 0;
        for (; kk < 140; kk += 4) {
            const float* wnp = wbase + (size_t)(kk + 4) * D_;
            float4 wn0 = *(const float4*)(wnp + 0 * D_);
            float4 wn1 = *(const float4*)(wnp + 1 * D_);
            float4 wn2 = *(const float4*)(wnp + 2 * D_);
            float4 wn3 = *(const float4*)(wnp + 3 * D_);
            fma16(wb0, *(const float4*)&xsT[kbeg + kk + 0][0]);
            fma16(wb1, *(const float4*)&xsT[kbeg + kk + 1][0]);
            fma16(wb2, *(const float4*)&xsT[kbeg + kk + 2][0]);
            fma16(wb3, *(const float4*)&xsT[kbeg + kk + 3][0]);
            wb0 = wn0; wb1 = wn1; wb2 = wn2; wb3 = wn3;
        }
        fma16(wb0, *(const float4*)&xsT[kbeg + 140][0]);
        fma16(wb1, *(const float4*)&xsT[kbeg + 141][0]);
        fma16(wb2, *(const float4*)&xsT[kbeg + 142][0]);
        fma16(wb3, *(const float4*)&xsT[kbeg + 143][0]);

        if (kg == 1) {
#pragma unroll
            for (int j = 0; j < 4; j++)
                *(float4*)&red[(j * 216 + ct) * 4] =
                    make_float4(a[j][0], a[j][1], a[j][2], a[j][3]);
        }
    }
    __syncthreads();

    if (active && kg == 0) {
        const int bb_ = base / L_;             // block never spans b boundary
        const int l0 = base % L_;
        float* outp = (m == 0) ? Q : (m == 1) ? K : V;
#pragma unroll
        for (int j = 0; j < 4; j++) {
            float4 o = *(const float4*)&red[(j * 216 + ct) * 4];
            a[j][0] += o.x; a[j][1] += o.y; a[j][2] += o.z; a[j][3] += o.w;
            int col = c + j;
            int h = col / DIM_, dd = col % DIM_;
#pragma unroll
            for (int r = 0; r < 4; r++) {
                int row = base + r;
                int b = row / L_, l = row % L_;
                outp[((size_t)(b * H_ + h) * L_ + l) * DIM_ + dd] = a[j][r];
            }
            if (m == 1) {
                *(float4*)(KT + ((size_t)(bb_ * H_ + h) * DIM_ + dd) * L_ + l0) =
                    make_float4(a[j][0], a[j][1], a[j][2], a[j][3]);
            }
        }
    }
}

// ---------------------------------------------------------------------------
// K1-fallback: qkv with row-major weights (small-ws path, no KT).
// ---------------------------------------------------------------------------
__global__ __launch_bounds__(320) void qkv_kernel(
    const float* __restrict__ x,
    const float* __restrict__ Wq, const float* __restrict__ bq,
    const float* __restrict__ Wk, const float* __restrict__ bk,
    const float* __restrict__ Wv, const float* __restrict__ bv,
    float* __restrict__ Q, float* __restrict__ K, float* __restrict__ V)
{
    constexpr int R = 8;
    __shared__ float xs[R][D_];
    const int base = blockIdx.x * R;
    const int tid = threadIdx.x;

    const float4* xsrc = (const float4*)(x + (size_t)base * D_);
    float4* xdst = (float4*)&xs[0][0];
    for (int i = tid; i < R * D_ / 4; i += 320) xdst[i] = xsrc[i];
    __syncthreads();

    if (tid < D_) {
        const float4* wq4 = (const float4*)(Wq + (size_t)tid * D_);
        const float4* wk4 = (const float4*)(Wk + (size_t)tid * D_);
        const float4* wv4 = (const float4*)(Wv + (size_t)tid * D_);
        float aq[R], ak[R], av[R];
        float biasq = bq[tid], biask = bk[tid], biasv = bv[tid];
#pragma unroll
        for (int r = 0; r < R; r++) { aq[r] = biasq; ak[r] = biask; av[r] = biasv; }
        for (int d4 = 0; d4 < D_ / 4; d4++) {
            float4 wqv = wq4[d4], wkv = wk4[d4], wvv = wv4[d4];
#pragma unroll
            for (int r = 0; r < R; r++) {
                float4 hv = *(const float4*)&xs[r][d4 * 4];
                aq[r] += dot4(hv, wqv);
                ak[r] += dot4(hv, wkv);
                av[r] += dot4(hv, wvv);
            }
        }
        const int h = tid / DIM_, dd = tid % DIM_;
#pragma unroll
        for (int r = 0; r < R; r++) {
            int row = base + r;
            int b = row / L_, l = row % L_;
            size_t o = ((size_t)(b * H_ + h) * L_ + l) * DIM_ + dd;
            Q[o] = aq[r]; K[o] = ak[r]; V[o] = av[r];
        }
    }
}

// ---------------------------------------------------------------------------
// K3: FUSED score+measure. grid 2000, block 256.
// ---------------------------------------------------------------------------
__global__ __launch_bounds__(256) void score_measure3_kernel(
    const float* __restrict__ Q, const float* __restrict__ KT,
    const int* __restrict__ index_key, float* __restrict__ measure)
{
    constexpr int R = 8;
    __shared__ float qs[R][DIM_];
    __shared__ float st[R][1004];
    const int bh = blockIdx.x / 125;
    const int qt = blockIdx.x % 125;
    const int tid = threadIdx.x;

    if (tid < R * DIM_ / 4)
        ((float4*)&qs[0][0])[tid] =
            ((const float4*)(Q + ((size_t)bh * L_ + qt * R) * DIM_))[tid];
    __syncthreads();

    const float* KTb = KT + (size_t)bh * DIM_ * L_;
#pragma unroll
    for (int i = 0; i < 4; i++) {
        const int k = i * 256 + tid;
        if (k < L_) {
            float acc[R];
#pragma unroll
            for (int r = 0; r < R; r++) acc[r] = 0.f;
#pragma unroll
            for (int d4 = 0; d4 < DIM_ / 4; d4++) {
                float4 kv;
                kv.x = KTb[(size_t)(d4 * 4 + 0) * L_ + k];
                kv.y = KTb[(size_t)(d4 * 4 + 1) * L_ + k];
                kv.z = KTb[(size_t)(d4 * 4 + 2) * L_ + k];
                kv.w = KTb[(size_t)(d4 * 4 + 3) * L_ + k];
#pragma unroll
                for (int r = 0; r < R; r++)
                    acc[r] += dot4(*(const float4*)&qs[r][d4 * 4], kv);
            }
#pragma unroll
            for (int r = 0; r < R; r++) st[r][k] = acc[r];
        }
    }
    __syncthreads();

    const int r = tid >> 5;             // 0..7
    const int lane = tid & 31;
    const int l = qt * R + r;
    const int* ik = index_key + l * KS_;
    float mx = -1e30f, sm = 0.f;
    for (int s = lane; s < KS_; s += 32) {
        float v = st[r][ik[s]];
        mx = fmaxf(mx, v);
        sm += v;
    }
#pragma unroll
    for (int off = 16; off; off >>= 1) {
        mx = fmaxf(mx, __shfl_xor(mx, off));
        sm += __shfl_xor(sm, off);
    }
    if (lane == 0) measure[bh * L_ + l] = mx - sm * (1.0f / (float)L_);
}

// ---------------------------------------------------------------------------
// K3-fallback: gather-based measure.
// ---------------------------------------------------------------------------
__global__ __launch_bounds__(256) void measure_kernel(
    const float* __restrict__ Q, const float* __restrict__ K,
    const int* __restrict__ index_key, float* __restrict__ measure)
{
    const int w = threadIdx.x >> 6;
    const int lane = threadIdx.x & 63;
    const int wid = blockIdx.x * 4 + w;
    const int bh = wid / L_;
    const int l = wid % L_;

    const float4* qp = (const float4*)(Q + ((size_t)bh * L_ + l) * DIM_);
    float4 q[9];
#pragma unroll
    for (int i = 0; i < 9; i++) q[i] = qp[i];

    const int* ik = index_key + l * KS_;
    const float* Kb = K + (size_t)bh * L_ * DIM_;

    float mx = -1e30f, sm = 0.f;
#pragma unroll
    for (int s = lane; s < KS_; s += 64) {
        int kidx = ik[s];
        const float4* k4 = (const float4*)(Kb + (size_t)kidx * DIM_);
        float acc = 0.f;
#pragma unroll
        for (int i = 0; i < 9; i++) acc += dot4(q[i], k4[i]);
        mx = fmaxf(mx, acc);
        sm += acc;
    }
#pragma unroll
    for (int off = 32; off; off >>= 1) {
        mx = fmaxf(mx, __shfl_xor(mx, off));
        sm += __shfl_xor(sm, off);
    }
    if (lane == 0) measure[wid] = mx - sm * (1.0f / (float)L_);
}

// ---------------------------------------------------------------------------
// K4+K2 merged: top-NQ rank-based (blocks 0..63) + Vmean (blocks 64..79).
// ---------------------------------------------------------------------------
__global__ __launch_bounds__(256) void topk_vmean_kernel(
    const float* __restrict__ measure, int* __restrict__ qlist,
    int* __restrict__ slot_map, const float* __restrict__ V,
    float* __restrict__ Vmean)
{
    if (blockIdx.x < BH_ * 4) {
        const int bh = blockIdx.x >> 2;
        const int quarter = blockIdx.x & 3;
        __shared__ float m[L_];
        for (int i = threadIdx.x; i < L_; i += 256) m[i] = measure[bh * L_ + i];
        __syncthreads();
        const int i = quarter * 250 + threadIdx.x;
        if (threadIdx.x < 250) {
            float mi = m[i];
            int rank = 0;
            for (int j = 0; j < L_; j++) {
                float mj = m[j];
                rank += (mj > mi) || (mj == mi && j < i);
            }
            if (rank < NQ_) qlist[bh * NQ_ + rank] = i;
            slot_map[bh * L_ + i] = (rank < NQ_) ? rank : -1;
        }
    } else {
        const int bh = blockIdx.x - BH_ * 4;
        const int tid = threadIdx.x;
        __shared__ float red2[7][DIM_];
        if (tid < 252) {
            int gq = tid / DIM_, d = tid % DIM_;
            const float* basep = V + (size_t)bh * L_ * DIM_;
            float s = 0.f;
            for (int l = gq; l < L_; l += 7) s += basep[l * DIM_ + d];
            red2[gq][d] = s;
        }
        __syncthreads();
        if (tid < DIM_) {
            float s = 0.f;
#pragma unroll
            for (int gq = 0; gq < 7; gq++) s += red2[gq][tid];
            Vmean[bh * DIM_ + tid] = s * (1.0f / L_);
        }
    }
}

// ---------------------------------------------------------------------------
// K6 v2: attention partials, K/V chunk staged in LDS. grid BH_*nchunk.
// ---------------------------------------------------------------------------
__global__ __launch_bounds__(256) void attn_part2_kernel(
    const float* __restrict__ Q, const float* __restrict__ K,
    const float* __restrict__ V, const int* __restrict__ qlist,
    float* __restrict__ part, int nchunk, int chunk_len)
{
    __shared__ float Ks[MAXCL_ * DIM_];
    __shared__ float Vs[MAXCL_ * DIM_];
    const int bh = blockIdx.x / nchunk;
    const int chunk = blockIdx.x % nchunk;
    const int tid = threadIdx.x;
    const int k0 = chunk * chunk_len;

    {
        const float4* Ksrc = (const float4*)(K + ((size_t)bh * L_ + k0) * DIM_);
        const float4* Vsrc = (const float4*)(V + ((size_t)bh * L_ + k0) * DIM_);
        const int nf4 = chunk_len * (DIM_ / 4);
        for (int i = tid; i < nf4; i += 256) {
            ((float4*)Ks)[i] = Ksrc[i];
            ((float4*)Vs)[i] = Vsrc[i];
        }
    }
    __syncthreads();

    const int slot = tid;
    if (slot >= NQ_) return;

    const int qidx = qlist[bh * NQ_ + slot];
    const float4* qp = (const float4*)(Q + ((size_t)bh * L_ + qidx) * DIM_);
    float4 q[9];
#pragma unroll
    for (int i = 0; i < 9; i++) q[i] = qp[i];

    const float scale = (float)(1.0 / 6.0);
    float4 acc[9];
#pragma unroll
    for (int i = 0; i < 9; i++) acc[i] = make_float4(0.f, 0.f, 0.f, 0.f);
    float sum = 0.f;

    for (int j = 0; j < chunk_len; j++) {
        const float4* kp = (const float4*)(Ks + j * DIM_);   // broadcast
        float s = 0.f;
#pragma unroll
        for (int i = 0; i < 9; i++) s += dot4(q[i], kp[i]);
        float e = __expf(s * scale);
        sum += e;
        const float4* vp = (const float4*)(Vs + j * DIM_);   // broadcast
#pragma unroll
        for (int i = 0; i < 9; i++) {
            float4 vv = vp[i];
            acc[i].x += e * vv.x;
            acc[i].y += e * vv.y;
            acc[i].z += e * vv.z;
            acc[i].w += e * vv.w;
        }
    }

    float* p = part + ((size_t)(bh * NQ_ + slot) * nchunk + chunk) * PSTRIDE_;
#pragma unroll
    for (int i = 0; i < 9; i++) ((float4*)p)[i] = acc[i];
    p[DIM_] = sum;
}

// ---------------------------------------------------------------------------
// K7+K8 fused: combine partials (or Vmean) + residual + LN1. grid 2000.
// ---------------------------------------------------------------------------
__global__ __launch_bounds__(320) void combine_ln1_kernel(
    const float* __restrict__ x, const float* __restrict__ part,
    const int* __restrict__ slot_map, const float* __restrict__ Vmean,
    const float* __restrict__ g, const float* __restrict__ bb,
    float* __restrict__ h1, int nchunk)
{
    const int row = blockIdx.x;          // 0..B_*L_-1
    const int b = row / L_, l = row % L_;
    const int tid = threadIdx.x;
    __shared__ float psum[5], pssq[5];

    float y = 0.f;
    if (tid < D_) {
        const int h = tid / DIM_, d = tid % DIM_;
        const int bh = b * H_ + h;
        const int slot = slot_map[bh * L_ + l];
        float v;
        if (slot < 0) {
            v = Vmean[bh * DIM_ + d];
        } else {
            const float* p = part + (size_t)(bh * NQ_ + slot) * nchunk * PSTRIDE_;
            float a = 0.f, s = 0.f;
            for (int c = 0; c < nchunk; c++) {
                a += p[c * PSTRIDE_ + d];
                s += p[c * PSTRIDE_ + DIM_];
            }
            v = a / s;
        }
        y = x[(size_t)row * D_ + tid] + v;
    }

    float s1 = y, s2 = y * y;
#pragma unroll
    for (int off = 32; off; off >>= 1) {
        s1 += __shfl_xor(s1, off);
        s2 += __shfl_xor(s2, off);
    }
    const int w = tid >> 6, lane = tid & 63;
    if (lane == 0) { psum[w] = s1; pssq[w] = s2; }
    __syncthreads();
    float ts = 0.f, tq = 0.f;
#pragma unroll
    for (int i = 0; i < 5; i++) { ts += psum[i]; tq += pssq[i]; }
    float mu = ts * (1.0f / D_);
    float var = tq * (1.0f / D_) - mu * mu;
    float rstd = rsqrtf(var + EPS_);
    if (tid < D_)
        h1[(size_t)row * D_ + tid] = (y - mu) * rstd * g[tid] + bb[tid];
}

// ---------------------------------------------------------------------------
// K9 v4p: fused FFN, R=4, block 576, grid 500. Phase1: 144 ct x 4 kg of 72.
// Phase2: 72 ct x 8 kg of 72. NEW: manual double-buffered weight-load
// batches in both phase loops (same exposed-latency fix as qkvT3).
// ---------------------------------------------------------------------------
__global__ __launch_bounds__(576) void ffn_fused4_kernel(
    const float* __restrict__ h1,
    const float* __restrict__ W1T, const float* __restrict__ b1,
    const float* __restrict__ W2T, const float* __restrict__ b2,
    const float* __restrict__ g, const float* __restrict__ bb,
    float* __restrict__ out)
{
    constexpr int R = 4;
    __shared__ float hsT[D_][R];      // 4608 B  [k][r]
    __shared__ float fsT[DFF_][R];    // 9216 B  [k][r]
    __shared__ float red[8064];       // 32256 B (max of 3*576*4, 7*288*4)
    __shared__ float ys[R][D_];       // 4608 B
    const int base = blockIdx.x * R;
    const int tid = threadIdx.x;

    for (int idx = tid; idx < R * D_; idx += 576) {
        int r = idx / D_, k = idx % D_;
        hsT[k][r] = h1[(size_t)(base + r) * D_ + k];
    }
    __syncthreads();

    // phase 1: f = gelu(h1 @ W1T + b1); 144 col-groups x 4 k-groups of 72
    {
        const int kg = tid / 144;          // 0..3
        const int ct = tid - kg * 144;     // 0..143
        const int c = 4 * ct;
        float a[4][4];
#pragma unroll
        for (int j = 0; j < 4; j++) {
            float bv = (kg == 0) ? b1[c + j] : 0.f;
#pragma unroll
            for (int r = 0; r < 4; r++) a[j][r] = bv;
        }
        auto fma16 = [&a](const float4 w, const float4 xv) {
            a[0][0] += w.x * xv.x; a[0][1] += w.x * xv.y; a[0][2] += w.x * xv.z; a[0][3] += w.x * xv.w;
            a[1][0] += w.y * xv.x; a[1][1] += w.y * xv.y; a[1][2] += w.y * xv.z; a[1][3] += w.y * xv.w;
            a[2][0] += w.z * xv.x; a[2][1] += w.z * xv.y; a[2][2] += w.z * xv.z; a[2][3] += w.z * xv.w;
            a[3][0] += w.w * xv.x; a[3][1] += w.w * xv.y; a[3][2] += w.w * xv.z; a[3][3] += w.w * xv.w;
        };
        const int kbeg = kg * 72;
        const float* wbase = W1T + (size_t)kbeg * DFF_ + c;
        float4 wb0 = *(const float4*)(wbase + 0 * DFF_);
        float4 wb1 = *(const float4*)(wbase + 1 * DFF_);
        float4 wb2 = *(const float4*)(wbase + 2 * DFF_);
        float4 wb3 = *(const float4*)(wbase + 3 * DFF_);
        int kk = 0;
        for (; kk < 68; kk += 4) {
            const float* wnp = wbase + (size_t)(kk + 4) * DFF_;
            float4 wn0 = *(const float4*)(wnp + 0 * DFF_);
            float4 wn1 = *(const float4*)(wnp + 1 * DFF_);
            float4 wn2 = *(const float4*)(wnp + 2 * DFF_);
            float4 wn3 = *(const float4*)(wnp + 3 * DFF_);
            fma16(wb0, *(const float4*)&hsT[kbeg + kk + 0][0]);
            fma16(wb1, *(const float4*)&hsT[kbeg + kk + 1][0]);
            fma16(wb2, *(const float4*)&hsT[kbeg + kk + 2][0]);
            fma16(wb3, *(const float4*)&hsT[kbeg + kk + 3][0]);
            wb0 = wn0; wb1 = wn1; wb2 = wn2; wb3 = wn3;
        }
        fma16(wb0, *(const float4*)&hsT[kbeg + 68][0]);
        fma16(wb1, *(const float4*)&hsT[kbeg + 69][0]);
        fma16(wb2, *(const float4*)&hsT[kbeg + 70][0]);
        fma16(wb3, *(const float4*)&hsT[kbeg + 71][0]);

        if (kg >= 1) {
#pragma unroll
            for (int j = 0; j < 4; j++)
                *(float4*)&red[(((kg - 1) * 576) + j * 144 + ct) * 4] =
                    make_float4(a[j][0], a[j][1], a[j][2], a[j][3]);
        }
        __syncthreads();
        if (kg == 0) {
#pragma unroll
            for (int j = 0; j < 4; j++) {
                float4 o0 = *(const float4*)&red[((0 * 576) + j * 144 + ct) * 4];
                float4 o1 = *(const float4*)&red[((1 * 576) + j * 144 + ct) * 4];
                float4 o2 = *(const float4*)&red[((2 * 576) + j * 144 + ct) * 4];
                float y0 = gelu_exact(a[j][0] + o0.x + o1.x + o2.x);
                float y1 = gelu_exact(a[j][1] + o0.y + o1.y + o2.y);
                float y2 = gelu_exact(a[j][2] + o0.z + o1.z + o2.z);
                float y3 = gelu_exact(a[j][3] + o0.w + o1.w + o2.w);
                *(float4*)&fsT[c + j][0] = make_float4(y0, y1, y2, y3);
            }
        }
    }
    __syncthreads();

    // phase 2: y = gelu(f @ W2T + b2) + h1; 72 col-groups x 8 k-groups of 72
    {
        const int kg = tid / 72;           // 0..7
        const int ct = tid - kg * 72;      // 0..71
        const int c = 4 * ct;
        float a[4][4];
#pragma unroll
        for (int j = 0; j < 4; j++) {
            float bv = (kg == 0) ? b2[c + j] : 0.f;
#pragma unroll
            for (int r = 0; r < 4; r++) a[j][r] = bv;
        }
        auto fma16 = [&a](const float4 w, const float4 fv) {
            a[0][0] += w.x * fv.x; a[0][1] += w.x * fv.y; a[0][2] += w.x * fv.z; a[0][3] += w.x * fv.w;
            a[1][0] += w.y * fv.x; a[1][1] += w.y * fv.y; a[1][2] += w.y * fv.z; a[1][3] += w.y * fv.w;
            a[2][0] += w.z * fv.x; a[2][1] += w.z * fv.y; a[2][2] += w.z * fv.z; a[2][3] += w.z * fv.w;
            a[3][0] += w.w * fv.x; a[3][1] += w.w * fv.y; a[3][2] += w.w * fv.z; a[3][3] += w.w * fv.w;
        };
        const int kbeg = kg * 72;
        const float* wbase = W2T + (size_t)kbeg * D_ + c;
        float4 wb0 = *(const float4*)(wbase + 0 * D_);
        float4 wb1 = *(const float4*)(wbase + 1 * D_);
        float4 wb2 = *(const float4*)(wbase + 2 * D_);
        float4 wb3 = *(const float4*)(wbase + 3 * D_);
        int kk = 0;
        for (; kk < 68; kk += 4) {
            const float* wnp = wbase + (size_t)(kk + 4) * D_;
            float4 wn0 = *(const float4*)(wnp + 0 * D_);
            float4 wn1 = *(const float4*)(wnp + 1 * D_);
            float4 wn2 = *(const float4*)(wnp + 2 * D_);
            float4 wn3 = *(const float4*)(wnp + 3 * D_);
            fma16(wb0, *(const float4*)&fsT[kbeg + kk + 0][0]);
            fma16(wb1, *(const float4*)&fsT[kbeg + kk + 1][0]);
            fma16(wb2, *(const float4*)&fsT[kbeg + kk + 2][0]);
            fma16(wb3, *(const float4*)&fsT[kbeg + kk + 3][0]);
            wb0 = wn0; wb1 = wn1; wb2 = wn2; wb3 = wn3;
        }
        fma16(wb0, *(const float4*)&fsT[kbeg + 68][0]);
        fma16(wb1, *(const float4*)&fsT[kbeg + 69][0]);
        fma16(wb2, *(const float4*)&fsT[kbeg + 70][0]);
        fma16(wb3, *(const float4*)&fsT[kbeg + 71][0]);

        if (kg >= 1) {
#pragma unroll
            for (int j = 0; j < 4; j++)
                *(float4*)&red[(((kg - 1) * 288) + j * 72 + ct) * 4] =
                    make_float4(a[j][0], a[j][1], a[j][2], a[j][3]);
        }
        __syncthreads();
        if (kg == 0) {
            float y[4][4];
#pragma unroll
            for (int j = 0; j < 4; j++) {
                float t0 = a[j][0], t1 = a[j][1], t2 = a[j][2], t3 = a[j][3];
#pragma unroll
                for (int kk2 = 0; kk2 < 7; kk2++) {
                    float4 o = *(const float4*)&red[((kk2 * 288) + j * 72 + ct) * 4];
                    t0 += o.x; t1 += o.y; t2 += o.z; t3 += o.w;
                }
                float4 hres = *(const float4*)&hsT[c + j][0];
                y[j][0] = gelu_exact(t0) + hres.x;
                y[j][1] = gelu_exact(t1) + hres.y;
                y[j][2] = gelu_exact(t2) + hres.z;
                y[j][3] = gelu_exact(t3) + hres.w;
            }
#pragma unroll
            for (int r = 0; r < 4; r++)
                *(float4*)&ys[r][c] = make_float4(y[0][r], y[1][r], y[2][r], y[3][r]);
        }
    }
    __syncthreads();

    // phase 3: LN2, waves 0..3, one row each
    const int w = tid >> 6;
    const int lane = tid & 63;
    if (w < 4) {
        const int r = w;
        float s = 0.f, ss = 0.f;
#pragma unroll
        for (int i = 0; i < 5; i++) {
            int j = lane + i * 64;
            if (j < D_) { float yv = ys[r][j]; s += yv; ss += yv * yv; }
        }
#pragma unroll
        for (int off = 32; off; off >>= 1) {
            s += __shfl_xor(s, off);
            ss += __shfl_xor(ss, off);
        }
        float mu = s * (1.0f / D_);
        float var = ss * (1.0f / D_) - mu * mu;
        float rstd = rsqrtf(var + EPS_);
        int row = base + r;
#pragma unroll
        for (int i = 0; i < 5; i++) {
            int j = lane + i * 64;
            if (j < D_)
                out[(size_t)row * D_ + j] = (ys[r][j] - mu) * rstd * g[j] + bb[j];
        }
    }
}

// ---------------------------------------------------------------------------
// K9-fallback: FFN layer 1, 3 cols/thread. grid 250, block 192.
// ---------------------------------------------------------------------------
__global__ __launch_bounds__(192) void ffn1_kernel(
    const float* __restrict__ h1,
    const float* __restrict__ W1, const float* __restrict__ b1,
    float* __restrict__ f1)
{
    constexpr int R = 8;
    __shared__ float hs[R][D_];
    const int base = blockIdx.x * R;
    const int tid = threadIdx.x;

    const float4* hsrc = (const float4*)(h1 + (size_t)base * D_);
    float4* hdst = (float4*)&hs[0][0];
    for (int i = tid; i < R * D_ / 4; i += 192) hdst[i] = hsrc[i];
    __syncthreads();

    const int j0 = tid, j1 = tid + 192, j2 = tid + 384;
    const float4* w0 = (const float4*)(W1 + (size_t)j0 * D_);
    const float4* w1 = (const float4*)(W1 + (size_t)j1 * D_);
    const float4* w2 = (const float4*)(W1 + (size_t)j2 * D_);
    float a0[R], a1[R], a2[R];
    float bb0 = b1[j0], bb1 = b1[j1], bb2 = b1[j2];
#pragma unroll
    for (int r = 0; r < R; r++) { a0[r] = bb0; a1[r] = bb1; a2[r] = bb2; }

    for (int d4 = 0; d4 < D_ / 4; d4++) {
        float4 x0 = w0[d4], x1 = w1[d4], x2 = w2[d4];
#pragma unroll
        for (int r = 0; r < R; r++) {
            float4 hv = *(const float4*)&hs[r][d4 * 4];
            a0[r] += dot4(hv, x0);
            a1[r] += dot4(hv, x1);
            a2[r] += dot4(hv, x2);
        }
    }
#pragma unroll
    for (int r = 0; r < R; r++) {
        size_t rowo = (size_t)(base + r) * DFF_;
        f1[rowo + j0] = gelu_exact(a0[r]);
        f1[rowo + j1] = gelu_exact(a1[r]);
        f1[rowo + j2] = gelu_exact(a2[r]);
    }
}

// ---------------------------------------------------------------------------
// K10-fallback: FFN layer 2 + residual + LN2 (non-transposed).
// ---------------------------------------------------------------------------
__global__ __launch_bounds__(320) void ffn2_ln_kernel(
    const float* __restrict__ f1, const float* __restrict__ h1,
    const float* __restrict__ W2, const float* __restrict__ b2,
    const float* __restrict__ g, const float* __restrict__ bb,
    float* __restrict__ out)
{
    constexpr int R = 8;
    __shared__ float fs[R][DFF_];
    __shared__ float hs[R][D_];
    __shared__ float ys[R][D_];
    const int base = blockIdx.x * R;
    const int tid = threadIdx.x;

    const float4* fsrc = (const float4*)(f1 + (size_t)base * DFF_);
    float4* fdst = (float4*)&fs[0][0];
    for (int i = tid; i < R * DFF_ / 4; i += 320) fdst[i] = fsrc[i];
    const float4* hsrc = (const float4*)(h1 + (size_t)base * D_);
    float4* hdst = (float4*)&hs[0][0];
    for (int i = tid; i < R * D_ / 4; i += 320) hdst[i] = hsrc[i];
    __syncthreads();

    if (tid < D_) {
        const float4* w4 = (const float4*)(W2 + (size_t)tid * DFF_);
        float acc[R];
        float bias = b2[tid];
#pragma unroll
        for (int r = 0; r < R; r++) acc[r] = bias;
        for (int d4 = 0; d4 < DFF_ / 4; d4++) {
            float4 wv = w4[d4];
#pragma unroll
            for (int r = 0; r < R; r++) {
                float4 fv = *(const float4*)&fs[r][d4 * 4];
                acc[r] += dot4(fv, wv);
            }
        }
#pragma unroll
        for (int r = 0; r < R; r++) ys[r][tid] = gelu_exact(acc[r]) + hs[r][tid];
    }
    __syncthreads();

    const int w = tid >> 6;
    const int lane = tid & 63;
    for (int r = w; r < R; r += 5) {
        float s = 0.f, ss = 0.f;
#pragma unroll
        for (int i = 0; i < 5; i++) {
            int j = lane + i * 64;
            if (j < D_) { float y = ys[r][j]; s += y; ss += y * y; }
        }
#pragma unroll
        for (int off = 32; off; off >>= 1) {
            s += __shfl_xor(s, off);
            ss += __shfl_xor(ss, off);
        }
        float mu = s * (1.0f / D_);
        float var = ss * (1.0f / D_) - mu * mu;
        float rstd = rsqrtf(var + EPS_);
        int row = base + r;
#pragma unroll
        for (int i = 0; i < 5; i++) {
            int j = lane + i * 64;
            if (j < D_) out[(size_t)row * D_ + j] = (ys[r][j] - mu) * rstd * g[j] + bb[j];
        }
    }
}

// ---------------------------------------------------------------------------
extern "C" void kernel_launch(void* const* d_in, const int* in_sizes, int n_in,
                              void* d_out, int out_size, void* d_ws, size_t ws_size,
                              hipStream_t stream)
{
    const float* x         = (const float*)d_in[0];
    const int*   index_key = (const int*)  d_in[1];
    const float* Wq = (const float*)d_in[2];
    const float* bq = (const float*)d_in[3];
    const float* Wk = (const float*)d_in[4];
    const float* bk = (const float*)d_in[5];
    const float* Wv = (const float*)d_in[6];
    const float* bv = (const float*)d_in[7];
    const float* W1 = (const float*)d_in[8];
    const float* b1 = (const float*)d_in[9];
    const float* W2 = (const float*)d_in[10];
    const float* b2 = (const float*)d_in[11];
    const float* ln1_g = (const float*)d_in[12];
    const float* ln1_b = (const float*)d_in[13];
    const float* ln2_g = (const float*)d_in[14];
    const float* ln2_b = (const float*)d_in[15];
    float* out = (float*)d_out;

    // workspace carve (floats)
    float* Q        = (float*)d_ws;                      // 576000
    float* K        = Q + 576000;
    float* V        = K + 576000;
    float* Vmean    = V + 576000;                        // 576
    float* measure  = Vmean + 576;                       // 16000
    float* wtbuf    = measure + 16000;                   // 576000 (W1T/W2T live here)
    float* h1       = wtbuf + 576000;                    // 576000
    int*   qlist    = (int*)(h1 + 576000);               // 4000 ints
    int*   slot_map = qlist + 4000;                      // 16000 ints
    float* part     = (float*)(slot_map + 16000);        // 4,000,000
    float* f1       = part;                              // fallback only
    float* KT       = part + 4000000;                    // 576,000

    // transposed QKV weights alias the part region (dead until attn_part):
    float* WqT = part;
    float* WkT = WqT + 82944;
    float* WvT = WkT + 82944;
    // FFN transposed weights live in wtbuf (written at stream start, read last):
    float* W1T = wtbuf;                                  // 165888 floats
    float* W2T = wtbuf + 165888;                         // 165888 floats

    const size_t kt_end = 2916576ull + 4000000ull + 576000ull;  // ~30 MB
    const bool   big    = ws_size >= kt_end * sizeof(float);
    const int    nchunk = big ? 25 : 8;
    const int    chunk_len = L_ / nchunk;

    if (big) {
        weights_prep_kernel<<<567, 256, 0, stream>>>(Wq, Wk, Wv, WqT, WkT, WvT,
                                                     W1, W2, W1T, W2T);
        qkvT3_kernel<<<500, 448, 0, stream>>>(x, WqT, WkT, WvT, bq, bk, bv,
                                              Q, K, V, KT);
        score_measure3_kernel<<<BH_ * 125, 256, 0, stream>>>(Q, KT, index_key, measure);
    } else {
        qkv_kernel<<<250, 320, 0, stream>>>(x, Wq, bq, Wk, bk, Wv, bv, Q, K, V);
        measure_kernel<<<4000, 256, 0, stream>>>(Q, K, index_key, measure);
    }
    topk_vmean_kernel<<<BH_ * 4 + BH_, 256, 0, stream>>>(measure, qlist, slot_map, V, Vmean);
    attn_part2_kernel<<<BH_ * nchunk, 256, 0, stream>>>(Q, K, V, qlist, part, nchunk, chunk_len);
    combine_ln1_kernel<<<B_ * L_, 320, 0, stream>>>(x, part, slot_map, Vmean,
                                                    ln1_g, ln1_b, h1, nchunk);
    if (big) {
        ffn_fused4_kernel<<<500, 576, 0, stream>>>(h1, W1T, b1, W2T, b2,
                                                   ln2_g, ln2_b, out);
    } else {
        ffn1_kernel<<<250, 192, 0, stream>>>(h1, W1, b1, f1);
        ffn2_ln_kernel<<<250, 320, 0, stream>>>(f1, h1, W2, b2, ln2_g, ln2_b, out);
    }
}